// Round 2
// baseline (588.044 us; speedup 1.0000x reference)
//
#include <hip/hip_runtime.h>
#include <math.h>

#define HEADS   4
#define DH      32
#define NB      4096      // tokens per batch (D*H*W)
#define BATCH   2
#define C_IN    128
#define QKV_COLS 384
#define TOTROWS 8192      // BATCH * NB
#define SCALE   10.0f
#define ATT_EPS 1e-12f

// ---------------------------------------------------------------------------
// QKV GEMM (x @ w_qkv) + fused L2-normalize of q,k per head.
// grid 256 blocks, block 384 threads. Each block: 32 rows x 384 cols.
// Writes Q,K,V as [B][H][N][32].
// ---------------------------------------------------------------------------
__global__ __launch_bounds__(384) void qkv_kernel(
    const float* __restrict__ x, const float* __restrict__ w,
    float* __restrict__ Q, float* __restrict__ K, float* __restrict__ V) {
  __shared__ float xT[C_IN][36];   // transposed tile, stride 36 (16B-aligned rows)
  const int tid = threadIdx.x;
  const int r0  = blockIdx.x * 32;

  // load 32x128 x-tile, store transposed
  for (int i = tid; i < 32 * 32; i += 384) {     // 1024 float4s
    const int r = i >> 5, c4 = i & 31;
    const float4 v4 = ((const float4*)(x + (size_t)(r0 + r) * C_IN))[c4];
    xT[c4 * 4 + 0][r] = v4.x;
    xT[c4 * 4 + 1][r] = v4.y;
    xT[c4 * 4 + 2][r] = v4.z;
    xT[c4 * 4 + 3][r] = v4.w;
  }
  __syncthreads();

  float acc[32];
#pragma unroll
  for (int r = 0; r < 32; ++r) acc[r] = 0.f;

  for (int c = 0; c < C_IN; ++c) {
    const float wv = w[c * QKV_COLS + tid];
#pragma unroll
    for (int r4 = 0; r4 < 8; ++r4) {
      const float4 xv = *(const float4*)&xT[c][r4 * 4];   // broadcast read
      acc[r4 * 4 + 0] = fmaf(xv.x, wv, acc[r4 * 4 + 0]);
      acc[r4 * 4 + 1] = fmaf(xv.y, wv, acc[r4 * 4 + 1]);
      acc[r4 * 4 + 2] = fmaf(xv.z, wv, acc[r4 * 4 + 2]);
      acc[r4 * 4 + 3] = fmaf(xv.w, wv, acc[r4 * 4 + 3]);
    }
  }

  const int part = tid >> 7;   // 0=q, 1=k, 2=v  (uniform per wave: 384 = 6 waves)
  if (part < 2) {
    // L2-normalize across the 32 cols of each head (32-lane shuffle group)
#pragma unroll
    for (int r = 0; r < 32; ++r) {
      float s = acc[r] * acc[r];
      s += __shfl_xor(s, 1, 32);
      s += __shfl_xor(s, 2, 32);
      s += __shfl_xor(s, 4, 32);
      s += __shfl_xor(s, 8, 32);
      s += __shfl_xor(s, 16, 32);
      acc[r] *= 1.0f / fmaxf(sqrtf(s), ATT_EPS);
    }
  }

  float* dst = (part == 0) ? Q : (part == 1) ? K : V;
  const int h = (tid >> 5) & 3, d = tid & 31;
#pragma unroll
  for (int r = 0; r < 32; ++r) {
    const int rg = r0 + r;
    const int b  = rg >> 12;          // / NB
    const int n  = rg & (NB - 1);
    dst[((size_t)(b * HEADS + h) * NB + n) * DH + d] = acc[r];
  }
}

// ---------------------------------------------------------------------------
// fp32 flash attention, in-block split-K.
// grid (64 row-tiles, 8 bh), block 256 = 64 rows x 4 splits (1 wave per split).
// Each thread owns one q-row; split s covers j in [s*1024, (s+1)*1024).
// ---------------------------------------------------------------------------
__global__ __launch_bounds__(256) void attn_kernel(
    const float* __restrict__ Q, const float* __restrict__ K,
    const float* __restrict__ V, float* __restrict__ AO) {
  // per-split region: main loop: kt[1024] | vt[1024]; merge phase: 64 rows x 36
  __shared__ float smem[4][2304];   // 36.9 KB
  const int tid   = threadIdx.x;
  const int lane  = tid & 63;
  const int split = tid >> 6;
  const int bh    = blockIdx.y;
  const size_t base = (size_t)bh * NB * DH;
  const float* Qb = Q + base;
  const float* Kb = K + base;
  const float* Vb = V + base;
  const int row = blockIdx.x * 64 + lane;

  float q[32], o[32], p[32];
#pragma unroll
  for (int d4 = 0; d4 < 8; ++d4) {
    const float4 qv = ((const float4*)(Qb + (size_t)row * DH))[d4];
    q[d4 * 4 + 0] = qv.x; q[d4 * 4 + 1] = qv.y;
    q[d4 * 4 + 2] = qv.z; q[d4 * 4 + 3] = qv.w;
  }
#pragma unroll
  for (int d = 0; d < 32; ++d) o[d] = 0.f;
  float m = -1e30f, l = 0.f;

  float* kt = smem[split];
  float* vt = smem[split] + 1024;

  for (int t = 0; t < 32; ++t) {
    const int j0 = split * 1024 + t * 32;
    const float4* Ksrc = (const float4*)(Kb + (size_t)j0 * DH);
    const float4* Vsrc = (const float4*)(Vb + (size_t)j0 * DH);
#pragma unroll
    for (int u = 0; u < 4; ++u) {
      ((float4*)kt)[u * 64 + lane] = Ksrc[u * 64 + lane];
      ((float4*)vt)[u * 64 + lane] = Vsrc[u * 64 + lane];
    }
    __syncthreads();   // tile visible (also orders cross-lane LDS within wave)

    // S = q . K^T for 32 keys
#pragma unroll
    for (int j = 0; j < 32; ++j) {
      float a0 = 0.f, a1 = 0.f, a2 = 0.f, a3 = 0.f;
#pragma unroll
      for (int d4 = 0; d4 < 8; ++d4) {
        const float4 kv = *(const float4*)&kt[j * 32 + d4 * 4];  // broadcast
        a0 = fmaf(q[d4 * 4 + 0], kv.x, a0);
        a1 = fmaf(q[d4 * 4 + 1], kv.y, a1);
        a2 = fmaf(q[d4 * 4 + 2], kv.z, a2);
        a3 = fmaf(q[d4 * 4 + 3], kv.w, a3);
      }
      p[j] = (a0 + a1) + (a2 + a3);
    }

    // online softmax update
    float tmax = p[0];
#pragma unroll
    for (int j = 1; j < 32; ++j) tmax = fmaxf(tmax, p[j]);
    tmax *= SCALE;
    const float mnew = fmaxf(m, tmax);
    const float corr = __expf(m - mnew);
    l *= corr;
#pragma unroll
    for (int d = 0; d < 32; ++d) o[d] *= corr;
#pragma unroll
    for (int j = 0; j < 32; ++j) {
      const float e = __expf(fmaf(p[j], SCALE, -mnew));
      l += e;
      p[j] = e;
    }
    m = mnew;

    // O += P . V
#pragma unroll
    for (int j = 0; j < 32; ++j) {
      const float pj = p[j];
#pragma unroll
      for (int d4 = 0; d4 < 8; ++d4) {
        const float4 vv = *(const float4*)&vt[j * 32 + d4 * 4];  // broadcast
        o[d4 * 4 + 0] = fmaf(pj, vv.x, o[d4 * 4 + 0]);
        o[d4 * 4 + 1] = fmaf(pj, vv.y, o[d4 * 4 + 1]);
        o[d4 * 4 + 2] = fmaf(pj, vv.z, o[d4 * 4 + 2]);
        o[d4 * 4 + 3] = fmaf(pj, vv.w, o[d4 * 4 + 3]);
      }
    }
    __syncthreads();   // everyone done with tile before next overwrite
  }

  // publish per-split (m, l, o) for merge
  {
    float* mg = smem[split];
    mg[lane * 36 + 0] = m;
    mg[lane * 36 + 1] = l;
#pragma unroll
    for (int d = 0; d < 32; ++d) mg[lane * 36 + 4 + d] = o[d];
  }
  __syncthreads();

  // merge 4 splits: 256 threads = 64 rows x 4 d-chunks of 8
  {
    const int r = tid & 63;
    const int c = tid >> 6;
    float ms[4], ls[4];
#pragma unroll
    for (int s = 0; s < 4; ++s) {
      ms[s] = smem[s][r * 36 + 0];
      ls[s] = smem[s][r * 36 + 1];
    }
    float mm = fmaxf(fmaxf(ms[0], ms[1]), fmaxf(ms[2], ms[3]));
    float wgt[4], L = 0.f;
#pragma unroll
    for (int s = 0; s < 4; ++s) {
      wgt[s] = __expf(ms[s] - mm);
      L += wgt[s] * ls[s];
    }
    const float inv = 1.0f / L;
    const int rowg = blockIdx.x * 64 + r;
    const int b = bh >> 2, h = bh & 3;
    float* dst = AO + ((size_t)(b * NB + rowg)) * 128 + h * DH;
#pragma unroll
    for (int d = c * 8; d < c * 8 + 8; ++d) {
      float v = 0.f;
#pragma unroll
      for (int s = 0; s < 4; ++s) v += wgt[s] * smem[s][r * 36 + 4 + d];
      dst[d] = v * inv;
    }
  }
}

// ---------------------------------------------------------------------------
// out-proj GEMM: AO[8192][128] @ w_out[128][128] + b_out
// grid 256 blocks, block 128 threads. Each block: 32 rows x 128 cols.
// In-place safe (AO may alias out): each block stages its 32 rows in LDS
// before writing the same 32 rows; blocks touch disjoint rows.
// ---------------------------------------------------------------------------
__global__ __launch_bounds__(128) void outproj_kernel(
    const float* __restrict__ AO, const float* __restrict__ w,
    const float* __restrict__ bias, float* __restrict__ out) {
  __shared__ float xT[128][36];
  const int tid = threadIdx.x;
  const int r0  = blockIdx.x * 32;

  for (int i = tid; i < 32 * 32; i += 128) {
    const int r = i >> 5, c4 = i & 31;
    const float4 v4 = ((const float4*)(AO + (size_t)(r0 + r) * 128))[c4];
    xT[c4 * 4 + 0][r] = v4.x;
    xT[c4 * 4 + 1][r] = v4.y;
    xT[c4 * 4 + 2][r] = v4.z;
    xT[c4 * 4 + 3][r] = v4.w;
  }
  __syncthreads();

  float acc[32];
#pragma unroll
  for (int r = 0; r < 32; ++r) acc[r] = 0.f;

  for (int c = 0; c < 128; ++c) {
    const float wv = w[c * 128 + tid];
#pragma unroll
    for (int r4 = 0; r4 < 8; ++r4) {
      const float4 xv = *(const float4*)&xT[c][r4 * 4];
      acc[r4 * 4 + 0] = fmaf(xv.x, wv, acc[r4 * 4 + 0]);
      acc[r4 * 4 + 1] = fmaf(xv.y, wv, acc[r4 * 4 + 1]);
      acc[r4 * 4 + 2] = fmaf(xv.z, wv, acc[r4 * 4 + 2]);
      acc[r4 * 4 + 3] = fmaf(xv.w, wv, acc[r4 * 4 + 3]);
    }
  }

  const float bv = bias[tid];
#pragma unroll
  for (int r = 0; r < 32; ++r) {
    out[(size_t)(r0 + r) * 128 + tid] = acc[r] + bv;
  }
}

// ---------------------------------------------------------------------------
extern "C" void kernel_launch(void* const* d_in, const int* in_sizes, int n_in,
                              void* d_out, int out_size, void* d_ws, size_t ws_size,
                              hipStream_t stream) {
  const float* x     = (const float*)d_in[0];   // [2,8,16,32,128]
  const float* w_qkv = (const float*)d_in[1];   // [128,384]
  const float* w_out = (const float*)d_in[2];   // [128,128]
  const float* b_out = (const float*)d_in[3];   // [128]
  float* out = (float*)d_out;

  float* ws = (float*)d_ws;
  float* Q  = ws;                         // [2][4][4096][32] = 1,048,576 floats
  float* K  = ws + 1048576;
  float* V  = ws + 2097152;
  float* AO = out;                        // in-place: attn writes d_out, outproj
                                          // rewrites it (block-local staging)

  qkv_kernel<<<TOTROWS / 32, 384, 0, stream>>>(x, w_qkv, Q, K, V);
  attn_kernel<<<dim3(NB / 64, BATCH * HEADS), 256, 0, stream>>>(Q, K, V, AO);
  outproj_kernel<<<TOTROWS / 32, 128, 0, stream>>>(AO, w_out, b_out, out);
}

// Round 3
// 186.637 us; speedup vs baseline: 3.1507x; 3.1507x over previous
//
#include <hip/hip_runtime.h>
#include <math.h>

#define HEADS   4
#define DH      32
#define NB      4096      // tokens per batch (D*H*W)
#define BATCH   2
#define C_IN    128
#define QKV_COLS 384
#define TOTROWS 8192      // BATCH * NB
#define SCALE   10.0f
#define ATT_EPS 1e-12f
#define C1      14.42695040888963f   // SCALE * log2(e)

typedef __attribute__((ext_vector_type(16))) float f32x16;
typedef __attribute__((ext_vector_type(8)))  short short8;

__device__ __forceinline__ float tr16(float a) {        // truncate to bf16 (bits)
  return __uint_as_float(__float_as_uint(a) & 0xFFFF0000u);
}
__device__ __forceinline__ unsigned pkhi(float a, float b) {  // pack 2 bf16 (trunc)
  return (__float_as_uint(a) >> 16) | (__float_as_uint(b) & 0xFFFF0000u);
}
union U8 { unsigned u[4]; short8 s8; };
__device__ __forceinline__ short8 mk8(unsigned a, unsigned b, unsigned c, unsigned d) {
  U8 t; t.u[0] = a; t.u[1] = b; t.u[2] = c; t.u[3] = d; return t.s8;
}
__device__ __forceinline__ void split8(const float4& a, const float4& b,
                                       unsigned hf[4], unsigned lf[4]) {
  hf[0] = pkhi(a.x, a.y); hf[1] = pkhi(a.z, a.w);
  hf[2] = pkhi(b.x, b.y); hf[3] = pkhi(b.z, b.w);
  lf[0] = pkhi(a.x - tr16(a.x), a.y - tr16(a.y));
  lf[1] = pkhi(a.z - tr16(a.z), a.w - tr16(a.w));
  lf[2] = pkhi(b.x - tr16(b.x), b.y - tr16(b.y));
  lf[3] = pkhi(b.z - tr16(b.z), b.w - tr16(b.w));
}

// ---------------------------------------------------------------------------
// QKV GEMM (x @ w_qkv) + fused L2-normalize of q,k per head. (unchanged, passing)
// ---------------------------------------------------------------------------
__global__ __launch_bounds__(384) void qkv_kernel(
    const float* __restrict__ x, const float* __restrict__ w,
    float* __restrict__ Q, float* __restrict__ K, float* __restrict__ V) {
  __shared__ float xT[C_IN][36];
  const int tid = threadIdx.x;
  const int r0  = blockIdx.x * 32;

  for (int i = tid; i < 32 * 32; i += 384) {
    const int r = i >> 5, c4 = i & 31;
    const float4 v4 = ((const float4*)(x + (size_t)(r0 + r) * C_IN))[c4];
    xT[c4 * 4 + 0][r] = v4.x;
    xT[c4 * 4 + 1][r] = v4.y;
    xT[c4 * 4 + 2][r] = v4.z;
    xT[c4 * 4 + 3][r] = v4.w;
  }
  __syncthreads();

  float acc[32];
#pragma unroll
  for (int r = 0; r < 32; ++r) acc[r] = 0.f;

  for (int c = 0; c < C_IN; ++c) {
    const float wv = w[c * QKV_COLS + tid];
#pragma unroll
    for (int r4 = 0; r4 < 8; ++r4) {
      const float4 xv = *(const float4*)&xT[c][r4 * 4];
      acc[r4 * 4 + 0] = fmaf(xv.x, wv, acc[r4 * 4 + 0]);
      acc[r4 * 4 + 1] = fmaf(xv.y, wv, acc[r4 * 4 + 1]);
      acc[r4 * 4 + 2] = fmaf(xv.z, wv, acc[r4 * 4 + 2]);
      acc[r4 * 4 + 3] = fmaf(xv.w, wv, acc[r4 * 4 + 3]);
    }
  }

  const int part = tid >> 7;
  if (part < 2) {
#pragma unroll
    for (int r = 0; r < 32; ++r) {
      float s = acc[r] * acc[r];
      s += __shfl_xor(s, 1, 32);
      s += __shfl_xor(s, 2, 32);
      s += __shfl_xor(s, 4, 32);
      s += __shfl_xor(s, 8, 32);
      s += __shfl_xor(s, 16, 32);
      acc[r] *= 1.0f / fmaxf(sqrtf(s), ATT_EPS);
    }
  }

  float* dst = (part == 0) ? Q : (part == 1) ? K : V;
  const int h = (tid >> 5) & 3, d = tid & 31;
#pragma unroll
  for (int r = 0; r < 32; ++r) {
    const int rg = r0 + r;
    const int b  = rg >> 12;
    const int n  = rg & (NB - 1);
    dst[((size_t)(b * HEADS + h) * NB + n) * DH + d] = acc[r];
  }
}

// ---------------------------------------------------------------------------
// MFMA flash attention (bf16 hi/lo split, fp32-accurate).
// grid (64 q-pairs, 8 bh), block 256 = 4 waves = 2 q-subtiles x 2 KV-splits.
// Wave (split su, qsub u): 32 queries, keys [su*2048, su*2048+2048).
// Per 32-key tile: S^T = mfma(K, Q^T) 6x (hi/lo), in-register online softmax,
// O^T += mfma(V^T, P^T) 6x. LDS merge of the 2 splits at the end.
// ---------------------------------------------------------------------------
__global__ __launch_bounds__(256, 2) void attn_kernel(
    const float* __restrict__ Q, const float* __restrict__ K,
    const float* __restrict__ V, float* __restrict__ AO) {
  // [split][0=Khi 1=Klo 2=VThi 3=VTlo][2048B]  (32x32 bf16 tiles, slot-swizzled)
  __shared__ __align__(16) char sbuf[2][4][2048];
  __shared__ float smO[2][32][33];   // split-1 O^T publish: [qsub][q][d]
  __shared__ float smML[2][32][2];   // split-1 (m, L)

  const int tid  = threadIdx.x;
  const int lane = tid & 63;
  const int w    = tid >> 6;
  const int su   = w >> 1;          // this wave's split (compute role)
  const int u    = w & 1;           // q-subtile
  const int q    = lane & 31;       // query col / A-row index
  const int hi   = lane >> 5;
  const int bh   = blockIdx.y;
  const size_t base = (size_t)bh * NB * DH;
  const float* Qb = Q + base;
  const float* Kb = K + base;
  const float* Vb = V + base;

  // staging role (128 threads per split)
  const int ss = tid >> 7;
  const int r7 = tid & 127;
  const int keyA = r7 >> 3,        dqA = r7 & 7;
  const int keyB = (r7 + 128) >> 3, dqB = (r7 + 128) & 7;
  char* kh = sbuf[ss][0]; char* kl = sbuf[ss][1];
  char* vh = sbuf[ss][2]; char* vl = sbuf[ss][3];

  // ---- Q fragments (hi/lo split), B-operand layout: col=q, k=(hi*8 + e) ----
  const int nrow = blockIdx.x * 64 + u * 32 + q;
  const float* qrow = Qb + (size_t)nrow * DH;
  unsigned qhf[2][4], qlf[2][4];
#pragma unroll
  for (int sl = 0; sl < 2; ++sl) {
    const int d0 = sl * 16 + hi * 8;
    const float4 a = *(const float4*)(qrow + d0);
    const float4 b = *(const float4*)(qrow + d0 + 4);
    split8(a, b, qhf[sl], qlf[sl]);
  }

  f32x16 oa;
#pragma unroll
  for (int r = 0; r < 16; ++r) oa[r] = 0.f;
  float mrun = -1e30f, lrun = 0.f;

  float4 kA, kB, vA, vB;
  {
    const float* kp = Kb + (size_t)(ss * 2048) * DH;
    const float* vp = Vb + (size_t)(ss * 2048) * DH;
    kA = *(const float4*)(kp + keyA * DH + dqA * 4);
    kB = *(const float4*)(kp + keyB * DH + dqB * 4);
    vA = *(const float4*)(vp + keyA * DH + dqA * 4);
    vB = *(const float4*)(vp + keyB * DH + dqB * 4);
  }

  const char* ckh = sbuf[su][0]; const char* ckl = sbuf[su][1];
  const char* cvh = sbuf[su][2]; const char* cvl = sbuf[su][3];

  for (int t = 0; t < 64; ++t) {
    // ---- stage regs -> LDS (bf16 hi/lo; K row-major, V transposed) ----
    {
      // K fragments: row=key, 16B slot = d-block of 8; slot ^= (key>>1)&3
      {
        unsigned h0 = pkhi(kA.x, kA.y), h1 = pkhi(kA.z, kA.w);
        unsigned l0 = pkhi(kA.x - tr16(kA.x), kA.y - tr16(kA.y));
        unsigned l1 = pkhi(kA.z - tr16(kA.z), kA.w - tr16(kA.w));
        const int off = keyA * 64 + (((dqA >> 1) ^ ((keyA >> 1) & 3)) << 4) + (dqA & 1) * 8;
        *(uint2*)(kh + off) = make_uint2(h0, h1);
        *(uint2*)(kl + off) = make_uint2(l0, l1);
      }
      {
        unsigned h0 = pkhi(kB.x, kB.y), h1 = pkhi(kB.z, kB.w);
        unsigned l0 = pkhi(kB.x - tr16(kB.x), kB.y - tr16(kB.y));
        unsigned l1 = pkhi(kB.z - tr16(kB.z), kB.w - tr16(kB.w));
        const int off = keyB * 64 + (((dqB >> 1) ^ ((keyB >> 1) & 3)) << 4) + (dqB & 1) * 8;
        *(uint2*)(kh + off) = make_uint2(h0, h1);
        *(uint2*)(kl + off) = make_uint2(l0, l1);
      }
      // V transposed: vt[d][j], slot(j-block of 8) ^= (d>>1)&3
#pragma unroll
      for (int uu = 0; uu < 4; ++uu) {
        const int d = dqA * 4 + uu;
        const float x = (&vA.x)[uu];
        const int off = d * 64 + ((((keyA >> 3) ^ ((d >> 1) & 3))) << 4) + (keyA & 7) * 2;
        *(unsigned short*)(vh + off) = (unsigned short)(__float_as_uint(x) >> 16);
        const float xl = x - tr16(x);
        *(unsigned short*)(vl + off) = (unsigned short)(__float_as_uint(xl) >> 16);
      }
#pragma unroll
      for (int uu = 0; uu < 4; ++uu) {
        const int d = dqB * 4 + uu;
        const float x = (&vB.x)[uu];
        const int off = d * 64 + ((((keyB >> 3) ^ ((d >> 1) & 3))) << 4) + (keyB & 7) * 2;
        *(unsigned short*)(vh + off) = (unsigned short)(__float_as_uint(x) >> 16);
        const float xl = x - tr16(x);
        *(unsigned short*)(vl + off) = (unsigned short)(__float_as_uint(xl) >> 16);
      }
    }
    __syncthreads();

    // ---- prefetch next tile (overlaps compute) ----
    if (t < 63) {
      const float* kp = Kb + (size_t)(ss * 2048 + (t + 1) * 32) * DH;
      const float* vp = Vb + (size_t)(ss * 2048 + (t + 1) * 32) * DH;
      kA = *(const float4*)(kp + keyA * DH + dqA * 4);
      kB = *(const float4*)(kp + keyB * DH + dqB * 4);
      vA = *(const float4*)(vp + keyA * DH + dqA * 4);
      vB = *(const float4*)(vp + keyB * DH + dqB * 4);
    }

    // ---- QK^T: S^T[key][q], 3-term hi/lo split, accumulate over 2 d-slices ----
    f32x16 sa;
#pragma unroll
    for (int r = 0; r < 16; ++r) sa[r] = 0.f;
#pragma unroll
    for (int sl = 0; sl < 2; ++sl) {
      const int off = q * 64 + ((((sl * 2 + hi)) ^ ((q >> 1) & 3)) << 4);
      const short8 fkh = *(const short8*)(ckh + off);
      const short8 fkl = *(const short8*)(ckl + off);
      const short8 fqh = mk8(qhf[sl][0], qhf[sl][1], qhf[sl][2], qhf[sl][3]);
      const short8 fql = mk8(qlf[sl][0], qlf[sl][1], qlf[sl][2], qlf[sl][3]);
      sa = __builtin_amdgcn_mfma_f32_32x32x16_bf16(fkh, fqh, sa, 0, 0, 0);
      sa = __builtin_amdgcn_mfma_f32_32x32x16_bf16(fkl, fqh, sa, 0, 0, 0);
      sa = __builtin_amdgcn_mfma_f32_32x32x16_bf16(fkh, fql, sa, 0, 0, 0);
    }

    // ---- online softmax (scores*C1 in log2 domain), lane-resident query ----
    float pm = sa[0];
#pragma unroll
    for (int r = 1; r < 16; ++r) pm = fmaxf(pm, sa[r]);
    pm = fmaxf(pm, __shfl_xor(pm, 32));
    pm *= C1;
    const float mnew = fmaxf(mrun, pm);
    const float corr = exp2f(mrun - mnew);
    lrun *= corr;
#pragma unroll
    for (int r = 0; r < 16; ++r) oa[r] *= corr;
    mrun = mnew;
    float e[16]; float lsum = 0.f;
#pragma unroll
    for (int r = 0; r < 16; ++r) {
      e[r] = exp2f(fmaf(sa[r], C1, -mnew));
      lsum += e[r];
    }
    lrun += lsum;

    // ---- P split/pack -> B-frags, PV: O^T += V^T . P^T (3-term) ----
#pragma unroll
    for (int m = 0; m < 2; ++m) {
      const unsigned x0 = pkhi(e[8 * m + 0], e[8 * m + 1]);
      const unsigned x1 = pkhi(e[8 * m + 2], e[8 * m + 3]);
      const unsigned y0 = pkhi(e[8 * m + 4], e[8 * m + 5]);
      const unsigned y1 = pkhi(e[8 * m + 6], e[8 * m + 7]);
      const float f0 = e[8 * m + 0] - tr16(e[8 * m + 0]);
      const float f1 = e[8 * m + 1] - tr16(e[8 * m + 1]);
      const float f2 = e[8 * m + 2] - tr16(e[8 * m + 2]);
      const float f3 = e[8 * m + 3] - tr16(e[8 * m + 3]);
      const float f4 = e[8 * m + 4] - tr16(e[8 * m + 4]);
      const float f5 = e[8 * m + 5] - tr16(e[8 * m + 5]);
      const float f6 = e[8 * m + 6] - tr16(e[8 * m + 6]);
      const float f7 = e[8 * m + 7] - tr16(e[8 * m + 7]);
      const unsigned zx0 = pkhi(f0, f1), zx1 = pkhi(f2, f3);
      const unsigned zy0 = pkhi(f4, f5), zy1 = pkhi(f6, f7);
      const unsigned px0 = __shfl_xor(x0, 32), px1 = __shfl_xor(x1, 32);
      const unsigned py0 = __shfl_xor(y0, 32), py1 = __shfl_xor(y1, 32);
      const unsigned pzx0 = __shfl_xor(zx0, 32), pzx1 = __shfl_xor(zx1, 32);
      const unsigned pzy0 = __shfl_xor(zy0, 32), pzy1 = __shfl_xor(zy1, 32);
      const unsigned wh0 = hi ? py0 : x0;
      const unsigned wh1 = hi ? py1 : x1;
      const unsigned wh2 = hi ? y0 : px0;
      const unsigned wh3 = hi ? y1 : px1;
      const unsigned wl0 = hi ? pzy0 : zx0;
      const unsigned wl1 = hi ? pzy1 : zx1;
      const unsigned wl2 = hi ? zy0 : pzx0;
      const unsigned wl3 = hi ? zy1 : pzx1;
      const short8 fP  = mk8(wh0, wh1, wh2, wh3);
      const short8 fPl = mk8(wl0, wl1, wl2, wl3);
      const int voff = q * 64 + ((((m * 2 + hi)) ^ ((q >> 1) & 3)) << 4);
      const short8 fvh = *(const short8*)(cvh + voff);
      const short8 fvl = *(const short8*)(cvl + voff);
      oa = __builtin_amdgcn_mfma_f32_32x32x16_bf16(fvh, fP,  oa, 0, 0, 0);
      oa = __builtin_amdgcn_mfma_f32_32x32x16_bf16(fvl, fP,  oa, 0, 0, 0);
      oa = __builtin_amdgcn_mfma_f32_32x32x16_bf16(fvh, fPl, oa, 0, 0, 0);
    }
    __syncthreads();
  }

  // ---- merge the 2 splits via LDS ----
  const float Lfull = lrun + __shfl_xor(lrun, 32);
  if (su == 1) {
    if (hi == 0) { smML[u][q][0] = mrun; smML[u][q][1] = Lfull; }
#pragma unroll
    for (int r = 0; r < 16; ++r) {
      const int d = (r & 3) + 8 * (r >> 2) + 4 * hi;
      smO[u][q][d] = oa[r];
    }
  }
  __syncthreads();
  if (su == 0) {
    const float m1 = smML[u][q][0];
    const float L1 = smML[u][q][1];
    const float mm = fmaxf(mrun, m1);
    const float w0 = exp2f(mrun - mm);
    const float w1 = exp2f(m1 - mm);
    const float inv = 1.0f / (w0 * Lfull + w1 * L1);
    const int b = bh >> 2, h = bh & 3;
    float* dst = AO + ((size_t)(b * NB + nrow)) * 128 + h * DH;
#pragma unroll
    for (int r = 0; r < 16; ++r) {
      const int d = (r & 3) + 8 * (r >> 2) + 4 * hi;
      dst[d] = (w0 * oa[r] + w1 * smO[u][q][d]) * inv;
    }
  }
}

// ---------------------------------------------------------------------------
// out-proj GEMM: AO[8192][128] @ w_out[128][128] + b_out (in-place safe)
// ---------------------------------------------------------------------------
__global__ __launch_bounds__(128) void outproj_kernel(
    const float* __restrict__ AO, const float* __restrict__ w,
    const float* __restrict__ bias, float* __restrict__ out) {
  __shared__ float xT[128][36];
  const int tid = threadIdx.x;
  const int r0  = blockIdx.x * 32;

  for (int i = tid; i < 32 * 32; i += 128) {
    const int r = i >> 5, c4 = i & 31;
    const float4 v4 = ((const float4*)(AO + (size_t)(r0 + r) * 128))[c4];
    xT[c4 * 4 + 0][r] = v4.x;
    xT[c4 * 4 + 1][r] = v4.y;
    xT[c4 * 4 + 2][r] = v4.z;
    xT[c4 * 4 + 3][r] = v4.w;
  }
  __syncthreads();

  float acc[32];
#pragma unroll
  for (int r = 0; r < 32; ++r) acc[r] = 0.f;

  for (int c = 0; c < 128; ++c) {
    const float wv = w[c * 128 + tid];
#pragma unroll
    for (int r4 = 0; r4 < 8; ++r4) {
      const float4 xv = *(const float4*)&xT[c][r4 * 4];
      acc[r4 * 4 + 0] = fmaf(xv.x, wv, acc[r4 * 4 + 0]);
      acc[r4 * 4 + 1] = fmaf(xv.y, wv, acc[r4 * 4 + 1]);
      acc[r4 * 4 + 2] = fmaf(xv.z, wv, acc[r4 * 4 + 2]);
      acc[r4 * 4 + 3] = fmaf(xv.w, wv, acc[r4 * 4 + 3]);
    }
  }

  const float bv = bias[tid];
#pragma unroll
  for (int r = 0; r < 32; ++r) {
    out[(size_t)(r0 + r) * 128 + tid] = acc[r] + bv;
  }
}

// ---------------------------------------------------------------------------
extern "C" void kernel_launch(void* const* d_in, const int* in_sizes, int n_in,
                              void* d_out, int out_size, void* d_ws, size_t ws_size,
                              hipStream_t stream) {
  (void)in_sizes; (void)n_in; (void)out_size; (void)ws_size;
  const float* x     = (const float*)d_in[0];
  const float* w_qkv = (const float*)d_in[1];
  const float* w_out = (const float*)d_in[2];
  const float* b_out = (const float*)d_in[3];
  float* out = (float*)d_out;

  float* ws = (float*)d_ws;
  float* Q  = ws;                         // [2][4][4096][32]
  float* K  = ws + 1048576;
  float* V  = ws + 2097152;
  float* AO = out;                        // in-place (block-local staging in outproj)

  qkv_kernel<<<TOTROWS / 32, 384, 0, stream>>>(x, w_qkv, Q, K, V);
  attn_kernel<<<dim3(NB / 64, BATCH * HEADS), 256, 0, stream>>>(Q, K, V, AO);
  outproj_kernel<<<TOTROWS / 32, 128, 0, stream>>>(AO, w_out, b_out, out);
}

// Round 5
// 149.979 us; speedup vs baseline: 3.9209x; 1.2444x over previous
//
#include <hip/hip_runtime.h>
#include <math.h>

#define HEADS   4
#define DH      32
#define NB      4096      // tokens per batch (D*H*W)
#define BATCH   2
#define C_IN    128
#define QKV_COLS 384
#define TOTROWS 8192      // BATCH * NB
#define ATT_EPS 1e-12f
#define C1      14.42695040888963f   // SCALE * log2(e), prefolded into Q

typedef __attribute__((ext_vector_type(16))) float f32x16;
typedef __attribute__((ext_vector_type(8)))  short short8;
typedef unsigned short u16;

__device__ __forceinline__ float tr16(float a) {        // truncate to bf16 (bits)
  return __uint_as_float(__float_as_uint(a) & 0xFFFF0000u);
}
__device__ __forceinline__ unsigned pkhi(float a, float b) {  // pack 2 bf16 (trunc)
  return (__float_as_uint(a) >> 16) | (__float_as_uint(b) & 0xFFFF0000u);
}
__device__ __forceinline__ u16 b16(float a) {
  return (u16)(__float_as_uint(a) >> 16);
}
union U8 { unsigned u[4]; short8 s8; };
__device__ __forceinline__ short8 mk8(unsigned a, unsigned b, unsigned c, unsigned d) {
  U8 t; t.u[0] = a; t.u[1] = b; t.u[2] = c; t.u[3] = d; return t.s8;
}
// v_permlane32_swap_b32 a,b:  a'[hi32] = b[lo32], b'[lo32] = a[hi32].
// SAFE ONLY when a and b hold distinct values (else regalloc may coalesce
// them into one register and the swap degenerates) — see R4 post-mortem.
__device__ __forceinline__ void pl32swap(unsigned& a, unsigned& b) {
  asm("v_permlane32_swap_b32 %0, %1" : "+v"(a), "+v"(b));
}
#define GL16(gp, lp)                                                        \
  __builtin_amdgcn_global_load_lds(                                         \
      (const __attribute__((address_space(1))) void*)(gp),                  \
      (__attribute__((address_space(3))) void*)(lp), 16, 0, 0)

// ---------------------------------------------------------------------------
// QKV GEMM (x @ w_qkv) + fused L2-normalize of q,k. Writes:
//   Qs  fp32 [bh][n][32], pre-scaled by C1
//   Khi/Klo u16 [bh][n][32]   (bf16 truncation hi + residual lo)
//   VThi/VTlo u16 [bh][32][n] (pre-transposed)
// ---------------------------------------------------------------------------
__global__ __launch_bounds__(384) void qkv_kernel(
    const float* __restrict__ x, const float* __restrict__ w,
    float* __restrict__ Qs, u16* __restrict__ Khi, u16* __restrict__ Klo,
    u16* __restrict__ VThi, u16* __restrict__ VTlo) {
  __shared__ float xT[C_IN][36];
  const int tid = threadIdx.x;
  const int r0  = blockIdx.x * 32;

  for (int i = tid; i < 32 * 32; i += 384) {
    const int r = i >> 5, c4 = i & 31;
    const float4 v4 = ((const float4*)(x + (size_t)(r0 + r) * C_IN))[c4];
    xT[c4 * 4 + 0][r] = v4.x;
    xT[c4 * 4 + 1][r] = v4.y;
    xT[c4 * 4 + 2][r] = v4.z;
    xT[c4 * 4 + 3][r] = v4.w;
  }
  __syncthreads();

  float acc[32];
#pragma unroll
  for (int r = 0; r < 32; ++r) acc[r] = 0.f;

  for (int c = 0; c < C_IN; ++c) {
    const float wv = w[c * QKV_COLS + tid];
#pragma unroll
    for (int r4 = 0; r4 < 8; ++r4) {
      const float4 xv = *(const float4*)&xT[c][r4 * 4];
      acc[r4 * 4 + 0] = fmaf(xv.x, wv, acc[r4 * 4 + 0]);
      acc[r4 * 4 + 1] = fmaf(xv.y, wv, acc[r4 * 4 + 1]);
      acc[r4 * 4 + 2] = fmaf(xv.z, wv, acc[r4 * 4 + 2]);
      acc[r4 * 4 + 3] = fmaf(xv.w, wv, acc[r4 * 4 + 3]);
    }
  }

  const int part = tid >> 7;   // 0=q 1=k 2=v (wave-uniform)
  if (part < 2) {
#pragma unroll
    for (int r = 0; r < 32; ++r) {
      float s = acc[r] * acc[r];
      s += __shfl_xor(s, 1, 32);
      s += __shfl_xor(s, 2, 32);
      s += __shfl_xor(s, 4, 32);
      s += __shfl_xor(s, 8, 32);
      s += __shfl_xor(s, 16, 32);
      acc[r] *= 1.0f / fmaxf(sqrtf(s), ATT_EPS);
    }
  }

  const int h = (tid >> 5) & 3, d = tid & 31;
  const int b = r0 >> 12, n0 = r0 & (NB - 1);
  const int bh = b * HEADS + h;
  if (part == 0) {
    float* dst = Qs + ((size_t)bh * NB + n0) * DH + d;
#pragma unroll
    for (int r = 0; r < 32; ++r) dst[(size_t)r * DH] = acc[r] * C1;
  } else if (part == 1) {
    const size_t kb = ((size_t)bh * NB + n0) * DH + d;
#pragma unroll
    for (int r = 0; r < 32; ++r) {
      const float kv = acc[r];
      Khi[kb + (size_t)r * DH] = b16(kv);
      Klo[kb + (size_t)r * DH] = b16(kv - tr16(kv));
    }
  } else {
    const size_t vb = ((size_t)bh * DH + d) * NB + n0;
#pragma unroll
    for (int r = 0; r < 32; r += 4) {
      uint2 hv, lv;
      hv.x = pkhi(acc[r + 0], acc[r + 1]);
      hv.y = pkhi(acc[r + 2], acc[r + 3]);
      lv.x = pkhi(acc[r + 0] - tr16(acc[r + 0]), acc[r + 1] - tr16(acc[r + 1]));
      lv.y = pkhi(acc[r + 2] - tr16(acc[r + 2]), acc[r + 3] - tr16(acc[r + 3]));
      *(uint2*)(VThi + vb + r) = hv;
      *(uint2*)(VTlo + vb + r) = lv;
    }
  }
}

// ---------------------------------------------------------------------------
// MFMA flash attention. grid (64 q-pairs, 8 bh), block 256 = 4 waves
// = 2 q-subtiles x 2 KV-splits. Double-buffered LDS staged via
// global_load_lds with pre-swizzled per-lane global source addresses
// (linear LDS dest; read-side applies the same XOR swizzle).
// ---------------------------------------------------------------------------
__global__ __launch_bounds__(256, 2) void attn_kernel(
    const float* __restrict__ Qs,
    const u16* __restrict__ Khi, const u16* __restrict__ Klo,
    const u16* __restrict__ VThi, const u16* __restrict__ VTlo,
    float* __restrict__ AO) {
  // [buf][split][plane: 0=Khi 1=Klo 2=VThi 3=VTlo][2048B]
  __shared__ __align__(16) char sbuf[2][2][4][2048];   // 32 KB
  __shared__ float smO[2][32][33];
  __shared__ float smML[2][32][2];

  const int tid  = threadIdx.x;
  const int lane = tid & 63;
  const int w    = tid >> 6;
  const int su   = w >> 1;          // KV split
  const int u    = w & 1;           // q-subtile (and staging role: 0=K, 1=VT)
  const int q    = lane & 31;
  const int hi   = lane >> 5;
  const int bh   = blockIdx.y;

  // ---- Q fragments (hi/lo truncation split); Q pre-scaled by C1 ----
  const int nrow = blockIdx.x * 64 + u * 32 + q;
  const float* qrow = Qs + ((size_t)bh * NB + nrow) * DH;
  short8 fqh[2], fql[2];
#pragma unroll
  for (int sl = 0; sl < 2; ++sl) {
    const int d0 = sl * 16 + hi * 8;
    const float4 a = *(const float4*)(qrow + d0);
    const float4 b = *(const float4*)(qrow + d0 + 4);
    fqh[sl] = mk8(pkhi(a.x, a.y), pkhi(a.z, a.w), pkhi(b.x, b.y), pkhi(b.z, b.w));
    fql[sl] = mk8(pkhi(a.x - tr16(a.x), a.y - tr16(a.y)),
                  pkhi(a.z - tr16(a.z), a.w - tr16(a.w)),
                  pkhi(b.x - tr16(b.x), b.y - tr16(b.y)),
                  pkhi(b.z - tr16(b.z), b.w - tr16(b.w)));
  }

  // ---- staging source addresses (pre-swizzled; LDS dest is linear) ----
  const int rt  = lane >> 2;          // row 0..15 (plus +16 on second call)
  const int p   = lane & 3;           // physical 16B slot
  const int sw0 = (rt >> 1) & 3;
  const int sw1 = ((rt + 16) >> 1) & 3;
  const u16 *g0, *g1, *g2, *g3;
  int gstep;
  if (u == 0) {   // K planes: row=key (64B), tile advances 32 keys
    const size_t pb = (size_t)bh * NB * DH + (size_t)su * 2048 * DH;
    const int o0 = rt * DH + ((p ^ sw0) << 3);
    const int o1 = (rt + 16) * DH + ((p ^ sw1) << 3);
    g0 = Khi + pb + o0; g1 = Khi + pb + o1;
    g2 = Klo + pb + o0; g3 = Klo + pb + o1;
    gstep = 32 * DH;
  } else {        // VT planes: row=d (NB-long), tile advances 32 u16 within row
    const size_t pb = (size_t)bh * DH * NB + (size_t)su * 2048;
    const int o0 = rt * NB + ((p ^ sw0) << 3);
    const int o1 = (rt + 16) * NB + ((p ^ sw1) << 3);
    g0 = VThi + pb + o0; g1 = VThi + pb + o1;
    g2 = VTlo + pb + o0; g3 = VTlo + pb + o1;
    gstep = 32;
  }
  char* const sb = (char*)sbuf;
  const int myplanes = ((su << 2) + u * 2) * 2048;    // offset of this wave's hi-plane
  auto stage = [&](int buf) {
    char* ph = sb + buf * 16384 + myplanes;
    char* pl = ph + 2048;
    GL16(g0, ph); GL16(g1, ph + 1024);
    GL16(g2, pl); GL16(g3, pl + 1024);
    g0 += gstep; g1 += gstep; g2 += gstep; g3 += gstep;
  };

  // read offsets (swizzled), constant per wave
  const int swq = (q >> 1) & 3;
  int koff[2], voff[2];
#pragma unroll
  for (int i = 0; i < 2; ++i) {
    koff[i] = q * 64 + (((i * 2 + hi) ^ swq) << 4);
    voff[i] = koff[i];
  }

  f32x16 oa;
#pragma unroll
  for (int r = 0; r < 16; ++r) oa[r] = 0.f;
  float mrun = -1e30f, lrun = 0.f;

  stage(0);
  __syncthreads();

  for (int t = 0; t < 64; ++t) {
    const int cur = t & 1;
    if (t < 63) stage(cur ^ 1);

    const char* cb  = sb + cur * 16384 + (su << 2) * 2048;
    const char* ckh = cb;
    const char* ckl = cb + 2048;
    const char* cvh = cb + 4096;
    const char* cvl = cb + 6144;

    // ---- QK^T (3-term hi/lo), S^T[key][q] ----
    f32x16 sa;
#pragma unroll
    for (int r = 0; r < 16; ++r) sa[r] = 0.f;
#pragma unroll
    for (int sl = 0; sl < 2; ++sl) {
      const short8 fkh = *(const short8*)(ckh + koff[sl]);
      const short8 fkl = *(const short8*)(ckl + koff[sl]);
      sa = __builtin_amdgcn_mfma_f32_32x32x16_bf16(fkh, fqh[sl], sa, 0, 0, 0);
      sa = __builtin_amdgcn_mfma_f32_32x32x16_bf16(fkl, fqh[sl], sa, 0, 0, 0);
      sa = __builtin_amdgcn_mfma_f32_32x32x16_bf16(fkh, fql[sl], sa, 0, 0, 0);
    }

    // ---- online softmax (log2 domain; scores pre-scaled), defer-max ----
    float pm = sa[0];
#pragma unroll
    for (int r = 1; r < 16; ++r) pm = fmaxf(pm, sa[r]);
    pm = fmaxf(pm, __shfl_xor(pm, 32));   // cross-half row max (R4 bug was here)
    if (__any(pm > mrun + 8.0f)) {
      const float mnew = fmaxf(mrun, pm);
      const float corr = exp2f(mrun - mnew);
      lrun *= corr;
#pragma unroll
      for (int r = 0; r < 16; ++r) oa[r] *= corr;
      mrun = mnew;
    }
    float e[16], lsum = 0.f;
#pragma unroll
    for (int r = 0; r < 16; ++r) {
      e[r] = exp2f(sa[r] - mrun);
      lsum += e[r];
    }
    lrun += lsum;

    // ---- P pack (hi/lo) + permlane32_swap distribution, PV 3-term ----
#pragma unroll
    for (int m = 0; m < 2; ++m) {
      const float* eb = e + 8 * m;
      unsigned x0 = pkhi(eb[0], eb[1]), x1 = pkhi(eb[2], eb[3]);
      unsigned y0 = pkhi(eb[4], eb[5]), y1 = pkhi(eb[6], eb[7]);
      unsigned zx0 = pkhi(eb[0] - tr16(eb[0]), eb[1] - tr16(eb[1]));
      unsigned zx1 = pkhi(eb[2] - tr16(eb[2]), eb[3] - tr16(eb[3]));
      unsigned zy0 = pkhi(eb[4] - tr16(eb[4]), eb[5] - tr16(eb[5]));
      unsigned zy1 = pkhi(eb[6] - tr16(eb[6]), eb[7] - tr16(eb[7]));
      pl32swap(x0, y0);    // distinct values: safe
      pl32swap(x1, y1);
      pl32swap(zx0, zy0);
      pl32swap(zx1, zy1);
      const short8 fP  = mk8(x0, x1, y0, y1);
      const short8 fPl = mk8(zx0, zx1, zy0, zy1);
      const short8 fvh = *(const short8*)(cvh + voff[m]);
      const short8 fvl = *(const short8*)(cvl + voff[m]);
      oa = __builtin_amdgcn_mfma_f32_32x32x16_bf16(fvh, fP,  oa, 0, 0, 0);
      oa = __builtin_amdgcn_mfma_f32_32x32x16_bf16(fvl, fP,  oa, 0, 0, 0);
      oa = __builtin_amdgcn_mfma_f32_32x32x16_bf16(fvh, fPl, oa, 0, 0, 0);
    }
    __syncthreads();   // drains gload_lds (implicit vmcnt(0)) + LDS reads
  }

  // ---- merge the 2 splits via LDS ----
  const float Lfull = lrun + __shfl_xor(lrun, 32);
  if (su == 1) {
    if (hi == 0) { smML[u][q][0] = mrun; smML[u][q][1] = Lfull; }
#pragma unroll
    for (int r = 0; r < 16; ++r) {
      const int d = (r & 3) + 8 * (r >> 2) + 4 * hi;
      smO[u][q][d] = oa[r];
    }
  }
  __syncthreads();
  if (su == 0) {
    const float m1 = smML[u][q][0];
    const float L1 = smML[u][q][1];
    const float mm = fmaxf(mrun, m1);
    const float w0 = exp2f(mrun - mm);
    const float w1 = exp2f(m1 - mm);
    const float inv = 1.0f / (w0 * Lfull + w1 * L1);
    const int b = bh >> 2, h = bh & 3;
    float* dst = AO + ((size_t)(b * NB + nrow)) * 128 + h * DH;
#pragma unroll
    for (int r = 0; r < 16; ++r) {
      const int d = (r & 3) + 8 * (r >> 2) + 4 * hi;
      dst[d] = (w0 * oa[r] + w1 * smO[u][q][d]) * inv;
    }
  }
}

// ---------------------------------------------------------------------------
// out-proj GEMM: AO[8192][128] @ w_out[128][128] + b_out (in-place safe)
// ---------------------------------------------------------------------------
__global__ __launch_bounds__(128) void outproj_kernel(
    const float* __restrict__ AO, const float* __restrict__ w,
    const float* __restrict__ bias, float* __restrict__ out) {
  __shared__ float xT[128][36];
  const int tid = threadIdx.x;
  const int r0  = blockIdx.x * 32;

  for (int i = tid; i < 32 * 32; i += 128) {
    const int r = i >> 5, c4 = i & 31;
    const float4 v4 = ((const float4*)(AO + (size_t)(r0 + r) * 128))[c4];
    xT[c4 * 4 + 0][r] = v4.x;
    xT[c4 * 4 + 1][r] = v4.y;
    xT[c4 * 4 + 2][r] = v4.z;
    xT[c4 * 4 + 3][r] = v4.w;
  }
  __syncthreads();

  float acc[32];
#pragma unroll
  for (int r = 0; r < 32; ++r) acc[r] = 0.f;

  for (int c = 0; c < 128; ++c) {
    const float wv = w[c * 128 + tid];
#pragma unroll
    for (int r4 = 0; r4 < 8; ++r4) {
      const float4 xv = *(const float4*)&xT[c][r4 * 4];
      acc[r4 * 4 + 0] = fmaf(xv.x, wv, acc[r4 * 4 + 0]);
      acc[r4 * 4 + 1] = fmaf(xv.y, wv, acc[r4 * 4 + 1]);
      acc[r4 * 4 + 2] = fmaf(xv.z, wv, acc[r4 * 4 + 2]);
      acc[r4 * 4 + 3] = fmaf(xv.w, wv, acc[r4 * 4 + 3]);
    }
  }

  const float bv = bias[tid];
#pragma unroll
  for (int r = 0; r < 32; ++r) {
    out[(size_t)(r0 + r) * 128 + tid] = acc[r] + bv;
  }
}

// ---------------------------------------------------------------------------
extern "C" void kernel_launch(void* const* d_in, const int* in_sizes, int n_in,
                              void* d_out, int out_size, void* d_ws, size_t ws_size,
                              hipStream_t stream) {
  (void)in_sizes; (void)n_in; (void)out_size; (void)ws_size;
  const float* x     = (const float*)d_in[0];
  const float* w_qkv = (const float*)d_in[1];
  const float* w_out = (const float*)d_in[2];
  const float* b_out = (const float*)d_in[3];
  float* out = (float*)d_out;

  float* ws = (float*)d_ws;
  float* Qs = ws;                               // 4 MB fp32 [bh][n][32]
  u16* Khi  = (u16*)(ws + 1048576);             // 2 MB each
  u16* Klo  = Khi  + 1048576;
  u16* VThi = Klo  + 1048576;
  u16* VTlo = VThi + 1048576;
  float* AO = out;                              // in-place

  qkv_kernel<<<TOTROWS / 32, 384, 0, stream>>>(x, w_qkv, Qs, Khi, Klo, VThi, VTlo);
  attn_kernel<<<dim3(NB / 64, BATCH * HEADS), 256, 0, stream>>>(Qs, Khi, Klo, VThi, VTlo, AO);
  outproj_kernel<<<TOTROWS / 32, 128, 0, stream>>>(AO, w_out, b_out, out);
}

// Round 6
// 130.423 us; speedup vs baseline: 4.5087x; 1.1499x over previous
//
#include <hip/hip_runtime.h>
#include <math.h>

#define HEADS   4
#define DH      32
#define NB      4096      // tokens per batch (D*H*W)
#define BATCH   2
#define C_IN    128
#define QKV_COLS 384
#define TOTROWS 8192      // BATCH * NB
#define ATT_EPS 1e-12f
#define C1      14.42695040888963f   // SCALE * log2(e), prefolded into Q

typedef __attribute__((ext_vector_type(16))) float f32x16;
typedef __attribute__((ext_vector_type(8)))  short short8;
typedef unsigned short u16;

__device__ __forceinline__ float tr16(float a) {        // truncate to bf16 (bits)
  return __uint_as_float(__float_as_uint(a) & 0xFFFF0000u);
}
__device__ __forceinline__ unsigned pkhi(float a, float b) {  // pack 2 bf16 (trunc)
  return (__float_as_uint(a) >> 16) | (__float_as_uint(b) & 0xFFFF0000u);
}
__device__ __forceinline__ u16 b16(float a) {
  return (u16)(__float_as_uint(a) >> 16);
}
// RTN pack of 2 f32 -> 2 bf16 in one instruction (word0 = a, word1 = b)
__device__ __forceinline__ unsigned cvtpk(float a, float b) {
  unsigned r;
  asm("v_cvt_pk_bf16_f32 %0, %1, %2" : "=v"(r) : "v"(a), "v"(b));
  return r;
}
union U8 { unsigned u[4]; short8 s8; };
__device__ __forceinline__ short8 mk8(unsigned a, unsigned b, unsigned c, unsigned d) {
  U8 t; t.u[0] = a; t.u[1] = b; t.u[2] = c; t.u[3] = d; return t.s8;
}
// v_permlane32_swap_b32 a,b. SAFE ONLY when a and b hold distinct values
// (else regalloc may coalesce them into one register) — see R4 post-mortem.
__device__ __forceinline__ void pl32swap(unsigned& a, unsigned& b) {
  asm("v_permlane32_swap_b32 %0, %1" : "+v"(a), "+v"(b));
}
#define GL16(gp, lp)                                                        \
  __builtin_amdgcn_global_load_lds(                                         \
      (const __attribute__((address_space(1))) void*)(gp),                  \
      (__attribute__((address_space(3))) void*)(lp), 16, 0, 0)

// ---------------------------------------------------------------------------
// QKV GEMM (x @ w_qkv) + fused L2-normalize of q,k. Writes:
//   Qs  fp32 [bh][n][32], pre-scaled by C1
//   Khi/Klo u16 [bh][n][32]   (bf16 truncation hi + residual lo)
//   VThi/VTlo u16 [bh][32][n] (pre-transposed)
// ---------------------------------------------------------------------------
__global__ __launch_bounds__(384) void qkv_kernel(
    const float* __restrict__ x, const float* __restrict__ w,
    float* __restrict__ Qs, u16* __restrict__ Khi, u16* __restrict__ Klo,
    u16* __restrict__ VThi, u16* __restrict__ VTlo) {
  __shared__ float xT[C_IN][36];
  const int tid = threadIdx.x;
  const int r0  = blockIdx.x * 32;

  for (int i = tid; i < 32 * 32; i += 384) {
    const int r = i >> 5, c4 = i & 31;
    const float4 v4 = ((const float4*)(x + (size_t)(r0 + r) * C_IN))[c4];
    xT[c4 * 4 + 0][r] = v4.x;
    xT[c4 * 4 + 1][r] = v4.y;
    xT[c4 * 4 + 2][r] = v4.z;
    xT[c4 * 4 + 3][r] = v4.w;
  }
  __syncthreads();

  float acc[32];
#pragma unroll
  for (int r = 0; r < 32; ++r) acc[r] = 0.f;

  for (int c = 0; c < C_IN; ++c) {
    const float wv = w[c * QKV_COLS + tid];
#pragma unroll
    for (int r4 = 0; r4 < 8; ++r4) {
      const float4 xv = *(const float4*)&xT[c][r4 * 4];
      acc[r4 * 4 + 0] = fmaf(xv.x, wv, acc[r4 * 4 + 0]);
      acc[r4 * 4 + 1] = fmaf(xv.y, wv, acc[r4 * 4 + 1]);
      acc[r4 * 4 + 2] = fmaf(xv.z, wv, acc[r4 * 4 + 2]);
      acc[r4 * 4 + 3] = fmaf(xv.w, wv, acc[r4 * 4 + 3]);
    }
  }

  const int part = tid >> 7;   // 0=q 1=k 2=v (wave-uniform)
  if (part < 2) {
#pragma unroll
    for (int r = 0; r < 32; ++r) {
      float s = acc[r] * acc[r];
      s += __shfl_xor(s, 1, 32);
      s += __shfl_xor(s, 2, 32);
      s += __shfl_xor(s, 4, 32);
      s += __shfl_xor(s, 8, 32);
      s += __shfl_xor(s, 16, 32);
      acc[r] *= 1.0f / fmaxf(sqrtf(s), ATT_EPS);
    }
  }

  const int h = (tid >> 5) & 3, d = tid & 31;
  const int b = r0 >> 12, n0 = r0 & (NB - 1);
  const int bh = b * HEADS + h;
  if (part == 0) {
    float* dst = Qs + ((size_t)bh * NB + n0) * DH + d;
#pragma unroll
    for (int r = 0; r < 32; ++r) dst[(size_t)r * DH] = acc[r] * C1;
  } else if (part == 1) {
    const size_t kb = ((size_t)bh * NB + n0) * DH + d;
#pragma unroll
    for (int r = 0; r < 32; ++r) {
      const float kv = acc[r];
      Khi[kb + (size_t)r * DH] = b16(kv);
      Klo[kb + (size_t)r * DH] = b16(kv - tr16(kv));
    }
  } else {
    const size_t vb = ((size_t)bh * DH + d) * NB + n0;
#pragma unroll
    for (int r = 0; r < 32; r += 4) {
      uint2 hv, lv;
      hv.x = pkhi(acc[r + 0], acc[r + 1]);
      hv.y = pkhi(acc[r + 2], acc[r + 3]);
      lv.x = pkhi(acc[r + 0] - tr16(acc[r + 0]), acc[r + 1] - tr16(acc[r + 1]));
      lv.y = pkhi(acc[r + 2] - tr16(acc[r + 2]), acc[r + 3] - tr16(acc[r + 3]));
      *(uint2*)(VThi + vb + r) = hv;
      *(uint2*)(VTlo + vb + r) = lv;
    }
  }
}

// ---------------------------------------------------------------------------
// MFMA flash attention with FIXED softmax max: after L2 norm |q.k| <= 1, so
// log2-domain scores are bounded by C1 — exp2(sa) never over/underflows and
// the implicit 2^-C1 cancels in O/L. No max tracking, no rescale.
// grid (64 q-pairs, 8 bh), block 256 = 4 waves = 2 q-subtiles x 2 KV-splits.
// Double-buffered LDS staged via global_load_lds (pre-swizzled global src,
// linear LDS dest; read side applies the same XOR swizzle).
// ---------------------------------------------------------------------------
__global__ __launch_bounds__(256, 2) void attn_kernel(
    const float* __restrict__ Qs,
    const u16* __restrict__ Khi, const u16* __restrict__ Klo,
    const u16* __restrict__ VThi, const u16* __restrict__ VTlo,
    float* __restrict__ AO) {
  // [buf][split][plane: 0=Khi 1=Klo 2=VThi 3=VTlo][2048B]
  __shared__ __align__(16) char sbuf[2][2][4][2048];   // 32 KB
  __shared__ float smO[2][32][33];
  __shared__ float smL[2][32];

  const int tid  = threadIdx.x;
  const int lane = tid & 63;
  const int w    = tid >> 6;
  const int su   = w >> 1;          // KV split
  const int u    = w & 1;           // q-subtile (and staging role: 0=K, 1=VT)
  const int q    = lane & 31;
  const int hi   = lane >> 5;
  const int bh   = blockIdx.y;

  // ---- Q fragments (hi/lo truncation split); Q pre-scaled by C1 ----
  const int nrow = blockIdx.x * 64 + u * 32 + q;
  const float* qrow = Qs + ((size_t)bh * NB + nrow) * DH;
  short8 fqh[2], fql[2];
#pragma unroll
  for (int sl = 0; sl < 2; ++sl) {
    const int d0 = sl * 16 + hi * 8;
    const float4 a = *(const float4*)(qrow + d0);
    const float4 b = *(const float4*)(qrow + d0 + 4);
    fqh[sl] = mk8(pkhi(a.x, a.y), pkhi(a.z, a.w), pkhi(b.x, b.y), pkhi(b.z, b.w));
    fql[sl] = mk8(pkhi(a.x - tr16(a.x), a.y - tr16(a.y)),
                  pkhi(a.z - tr16(a.z), a.w - tr16(a.w)),
                  pkhi(b.x - tr16(b.x), b.y - tr16(b.y)),
                  pkhi(b.z - tr16(b.z), b.w - tr16(b.w)));
  }

  // ---- staging source addresses (pre-swizzled; LDS dest is linear) ----
  const int rt  = lane >> 2;          // row 0..15 (plus +16 on second call)
  const int p   = lane & 3;           // physical 16B slot
  const int sw0 = (rt >> 1) & 3;
  const int sw1 = ((rt + 16) >> 1) & 3;
  const u16 *g0, *g1, *g2, *g3;
  int gstep;
  if (u == 0) {   // K planes: row=key (64B), tile advances 32 keys
    const size_t pb = (size_t)bh * NB * DH + (size_t)su * 2048 * DH;
    const int o0 = rt * DH + ((p ^ sw0) << 3);
    const int o1 = (rt + 16) * DH + ((p ^ sw1) << 3);
    g0 = Khi + pb + o0; g1 = Khi + pb + o1;
    g2 = Klo + pb + o0; g3 = Klo + pb + o1;
    gstep = 32 * DH;
  } else {        // VT planes: row=d (NB-long), tile advances 32 u16 within row
    const size_t pb = (size_t)bh * DH * NB + (size_t)su * 2048;
    const int o0 = rt * NB + ((p ^ sw0) << 3);
    const int o1 = (rt + 16) * NB + ((p ^ sw1) << 3);
    g0 = VThi + pb + o0; g1 = VThi + pb + o1;
    g2 = VTlo + pb + o0; g3 = VTlo + pb + o1;
    gstep = 32;
  }
  char* const sb = (char*)sbuf;
  const int myplanes = ((su << 2) + u * 2) * 2048;    // offset of this wave's hi-plane
  auto stage = [&](int buf) {
    char* ph = sb + buf * 16384 + myplanes;
    char* pl = ph + 2048;
    GL16(g0, ph); GL16(g1, ph + 1024);
    GL16(g2, pl); GL16(g3, pl + 1024);
    g0 += gstep; g1 += gstep; g2 += gstep; g3 += gstep;
  };

  // read offsets (swizzled), constant per wave
  const int swq = (q >> 1) & 3;
  int koff[2], voff[2];
#pragma unroll
  for (int i = 0; i < 2; ++i) {
    koff[i] = q * 64 + (((i * 2 + hi) ^ swq) << 4);
    voff[i] = koff[i];
  }

  f32x16 oa;
#pragma unroll
  for (int r = 0; r < 16; ++r) oa[r] = 0.f;
  float lrun = 0.f;

  stage(0);
  __syncthreads();

  for (int t = 0; t < 64; ++t) {
    const int cur = t & 1;
    if (t < 63) stage(cur ^ 1);

    const char* cb  = sb + cur * 16384 + (su << 2) * 2048;
    const char* ckh = cb;
    const char* ckl = cb + 2048;
    const char* cvh = cb + 4096;
    const char* cvl = cb + 6144;

    // ---- QK^T (3-term hi/lo), S^T[key][q] ----
    f32x16 sa;
#pragma unroll
    for (int r = 0; r < 16; ++r) sa[r] = 0.f;
#pragma unroll
    for (int sl = 0; sl < 2; ++sl) {
      const short8 fkh = *(const short8*)(ckh + koff[sl]);
      const short8 fkl = *(const short8*)(ckl + koff[sl]);
      sa = __builtin_amdgcn_mfma_f32_32x32x16_bf16(fkh, fqh[sl], sa, 0, 0, 0);
      sa = __builtin_amdgcn_mfma_f32_32x32x16_bf16(fkl, fqh[sl], sa, 0, 0, 0);
      sa = __builtin_amdgcn_mfma_f32_32x32x16_bf16(fkh, fql[sl], sa, 0, 0, 0);
    }

    // ---- softmax with fixed max: e = exp2(sa), sa <= C1 always ----
    float e[16], lsum = 0.f;
#pragma unroll
    for (int r = 0; r < 16; ++r) {
      e[r] = exp2f(sa[r]);
      lsum += e[r];
    }
    lrun += lsum;

    // ---- P pack (RTN cvt_pk) + permlane32_swap distribution, PV 2-term ----
#pragma unroll
    for (int m = 0; m < 2; ++m) {
      const float* eb = e + 8 * m;
      unsigned x0 = cvtpk(eb[0], eb[1]), x1 = cvtpk(eb[2], eb[3]);
      unsigned y0 = cvtpk(eb[4], eb[5]), y1 = cvtpk(eb[6], eb[7]);
      pl32swap(x0, y0);    // distinct values: safe
      pl32swap(x1, y1);
      const short8 fP  = mk8(x0, x1, y0, y1);
      const short8 fvh = *(const short8*)(cvh + voff[m]);
      const short8 fvl = *(const short8*)(cvl + voff[m]);
      oa = __builtin_amdgcn_mfma_f32_32x32x16_bf16(fvh, fP, oa, 0, 0, 0);
      oa = __builtin_amdgcn_mfma_f32_32x32x16_bf16(fvl, fP, oa, 0, 0, 0);
    }
    __syncthreads();   // drains gload_lds (implicit vmcnt(0)) + LDS reads
  }

  // ---- merge the 2 splits via LDS (plain sums — common fixed max) ----
  const float Lfull = lrun + __shfl_xor(lrun, 32);
  if (su == 1) {
    if (hi == 0) smL[u][q] = Lfull;
#pragma unroll
    for (int r = 0; r < 16; ++r) {
      const int d = (r & 3) + 8 * (r >> 2) + 4 * hi;
      smO[u][q][d] = oa[r];
    }
  }
  __syncthreads();
  if (su == 0) {
    const float inv = 1.0f / (Lfull + smL[u][q]);
    const int b = bh >> 2, h = bh & 3;
    float* dst = AO + ((size_t)(b * NB + nrow)) * 128 + h * DH;
#pragma unroll
    for (int r = 0; r < 16; ++r) {
      const int d = (r & 3) + 8 * (r >> 2) + 4 * hi;
      dst[d] = (oa[r] + smO[u][q][d]) * inv;
    }
  }
}

// ---------------------------------------------------------------------------
// out-proj GEMM: AO[8192][128] @ w_out[128][128] + b_out (in-place safe)
// ---------------------------------------------------------------------------
__global__ __launch_bounds__(128) void outproj_kernel(
    const float* __restrict__ AO, const float* __restrict__ w,
    const float* __restrict__ bias, float* __restrict__ out) {
  __shared__ float xT[128][36];
  const int tid = threadIdx.x;
  const int r0  = blockIdx.x * 32;

  for (int i = tid; i < 32 * 32; i += 128) {
    const int r = i >> 5, c4 = i & 31;
    const float4 v4 = ((const float4*)(AO + (size_t)(r0 + r) * 128))[c4];
    xT[c4 * 4 + 0][r] = v4.x;
    xT[c4 * 4 + 1][r] = v4.y;
    xT[c4 * 4 + 2][r] = v4.z;
    xT[c4 * 4 + 3][r] = v4.w;
  }
  __syncthreads();

  float acc[32];
#pragma unroll
  for (int r = 0; r < 32; ++r) acc[r] = 0.f;

  for (int c = 0; c < 128; ++c) {
    const float wv = w[c * 128 + tid];
#pragma unroll
    for (int r4 = 0; r4 < 8; ++r4) {
      const float4 xv = *(const float4*)&xT[c][r4 * 4];
      acc[r4 * 4 + 0] = fmaf(xv.x, wv, acc[r4 * 4 + 0]);
      acc[r4 * 4 + 1] = fmaf(xv.y, wv, acc[r4 * 4 + 1]);
      acc[r4 * 4 + 2] = fmaf(xv.z, wv, acc[r4 * 4 + 2]);
      acc[r4 * 4 + 3] = fmaf(xv.w, wv, acc[r4 * 4 + 3]);
    }
  }

  const float bv = bias[tid];
#pragma unroll
  for (int r = 0; r < 32; ++r) {
    out[(size_t)(r0 + r) * 128 + tid] = acc[r] + bv;
  }
}

// ---------------------------------------------------------------------------
extern "C" void kernel_launch(void* const* d_in, const int* in_sizes, int n_in,
                              void* d_out, int out_size, void* d_ws, size_t ws_size,
                              hipStream_t stream) {
  (void)in_sizes; (void)n_in; (void)out_size; (void)ws_size;
  const float* x     = (const float*)d_in[0];
  const float* w_qkv = (const float*)d_in[1];
  const float* w_out = (const float*)d_in[2];
  const float* b_out = (const float*)d_in[3];
  float* out = (float*)d_out;

  float* ws = (float*)d_ws;
  float* Qs = ws;                               // 4 MB fp32 [bh][n][32]
  u16* Khi  = (u16*)(ws + 1048576);             // 2 MB each
  u16* Klo  = Khi  + 1048576;
  u16* VThi = Klo  + 1048576;
  u16* VTlo = VThi + 1048576;
  float* AO = out;                              // in-place

  qkv_kernel<<<TOTROWS / 32, 384, 0, stream>>>(x, w_qkv, Qs, Khi, Klo, VThi, VTlo);
  attn_kernel<<<dim3(NB / 64, BATCH * HEADS), 256, 0, stream>>>(Qs, Khi, Klo, VThi, VTlo, AO);
  outproj_kernel<<<TOTROWS / 32, 128, 0, stream>>>(AO, w_out, b_out, out);
}

// Round 8
// 108.560 us; speedup vs baseline: 5.4168x; 1.2014x over previous
//
#include <hip/hip_runtime.h>
#include <math.h>

#define HEADS   4
#define DH      32
#define NB      4096      // tokens per batch (D*H*W)
#define BATCH   2
#define C_IN    128
#define QKV_COLS 384
#define TOTROWS 8192      // BATCH * NB
#define ATT_EPS 1e-12f
#define C1      14.42695040888963f   // SCALE * log2(e), prefolded into Q

typedef __attribute__((ext_vector_type(16))) float f32x16;
typedef __attribute__((ext_vector_type(8)))  short short8;
typedef _Float16 f16x8 __attribute__((ext_vector_type(8)));
typedef __fp16 fp16x2 __attribute__((ext_vector_type(2)));   // cvt_pkrtz return type
typedef unsigned short u16;

__device__ __forceinline__ float tr16(float a) {        // truncate to bf16 (bits)
  return __uint_as_float(__float_as_uint(a) & 0xFFFF0000u);
}
__device__ __forceinline__ unsigned pkhi(float a, float b) {  // pack 2 bf16 (trunc)
  return (__float_as_uint(a) >> 16) | (__float_as_uint(b) & 0xFFFF0000u);
}
__device__ __forceinline__ u16 b16(float a) {
  return (u16)(__float_as_uint(a) >> 16);
}
// pack 2 f32 -> 2 f16 (RTZ), single instruction
union Uh2 { fp16x2 h; unsigned u; };
__device__ __forceinline__ unsigned pkf16(float a, float b) {
  Uh2 t; t.h = __builtin_amdgcn_cvt_pkrtz(a, b); return t.u;
}
union U8 { unsigned u[4]; short8 s8; };
__device__ __forceinline__ short8 mk8(unsigned a, unsigned b, unsigned c, unsigned d) {
  U8 t; t.u[0] = a; t.u[1] = b; t.u[2] = c; t.u[3] = d; return t.s8;
}
union U8h { unsigned u[4]; f16x8 h8; };
__device__ __forceinline__ f16x8 mk8h(unsigned a, unsigned b, unsigned c, unsigned d) {
  U8h t; t.u[0] = a; t.u[1] = b; t.u[2] = c; t.u[3] = d; return t.h8;
}
// v_permlane32_swap_b32 a,b. SAFE ONLY when a and b hold distinct values
// (else regalloc may coalesce them into one register) — see R4 post-mortem.
__device__ __forceinline__ void pl32swap(unsigned& a, unsigned& b) {
  asm("v_permlane32_swap_b32 %0, %1" : "+v"(a), "+v"(b));
}
#define GL16(gp, lp)                                                        \
  __builtin_amdgcn_global_load_lds(                                         \
      (const __attribute__((address_space(1))) void*)(gp),                  \
      (__attribute__((address_space(3))) void*)(lp), 16, 0, 0)

// ---------------------------------------------------------------------------
// QKV GEMM (x @ w_qkv) + fused L2-normalize of q,k. Writes:
//   Qs  fp32 [bh][n][32], pre-scaled by C1
//   Khi/Klo u16 [bh][n][32]   (bf16 truncation hi + residual lo)
//   VT16 u16 [bh][32][n]      (fp16 RTZ, pre-transposed)
// ---------------------------------------------------------------------------
__global__ __launch_bounds__(384) void qkv_kernel(
    const float* __restrict__ x, const float* __restrict__ w,
    float* __restrict__ Qs, u16* __restrict__ Khi, u16* __restrict__ Klo,
    u16* __restrict__ VT16) {
  __shared__ float xT[C_IN][36];
  const int tid = threadIdx.x;
  const int r0  = blockIdx.x * 32;

  for (int i = tid; i < 32 * 32; i += 384) {
    const int r = i >> 5, c4 = i & 31;
    const float4 v4 = ((const float4*)(x + (size_t)(r0 + r) * C_IN))[c4];
    xT[c4 * 4 + 0][r] = v4.x;
    xT[c4 * 4 + 1][r] = v4.y;
    xT[c4 * 4 + 2][r] = v4.z;
    xT[c4 * 4 + 3][r] = v4.w;
  }
  __syncthreads();

  float acc[32];
#pragma unroll
  for (int r = 0; r < 32; ++r) acc[r] = 0.f;

  for (int c = 0; c < C_IN; ++c) {
    const float wv = w[c * QKV_COLS + tid];
#pragma unroll
    for (int r4 = 0; r4 < 8; ++r4) {
      const float4 xv = *(const float4*)&xT[c][r4 * 4];
      acc[r4 * 4 + 0] = fmaf(xv.x, wv, acc[r4 * 4 + 0]);
      acc[r4 * 4 + 1] = fmaf(xv.y, wv, acc[r4 * 4 + 1]);
      acc[r4 * 4 + 2] = fmaf(xv.z, wv, acc[r4 * 4 + 2]);
      acc[r4 * 4 + 3] = fmaf(xv.w, wv, acc[r4 * 4 + 3]);
    }
  }

  const int part = tid >> 7;   // 0=q 1=k 2=v (wave-uniform)
  if (part < 2) {
#pragma unroll
    for (int r = 0; r < 32; ++r) {
      float s = acc[r] * acc[r];
      s += __shfl_xor(s, 1, 32);
      s += __shfl_xor(s, 2, 32);
      s += __shfl_xor(s, 4, 32);
      s += __shfl_xor(s, 8, 32);
      s += __shfl_xor(s, 16, 32);
      acc[r] *= 1.0f / fmaxf(sqrtf(s), ATT_EPS);
    }
  }

  const int h = (tid >> 5) & 3, d = tid & 31;
  const int b = r0 >> 12, n0 = r0 & (NB - 1);
  const int bh = b * HEADS + h;
  if (part == 0) {
    float* dst = Qs + ((size_t)bh * NB + n0) * DH + d;
#pragma unroll
    for (int r = 0; r < 32; ++r) dst[(size_t)r * DH] = acc[r] * C1;
  } else if (part == 1) {
    const size_t kb = ((size_t)bh * NB + n0) * DH + d;
#pragma unroll
    for (int r = 0; r < 32; ++r) {
      const float kv = acc[r];
      Khi[kb + (size_t)r * DH] = b16(kv);
      Klo[kb + (size_t)r * DH] = b16(kv - tr16(kv));
    }
  } else {
    const size_t vb = ((size_t)bh * DH + d) * NB + n0;
#pragma unroll
    for (int r = 0; r < 32; r += 4) {
      uint2 hv;
      hv.x = pkf16(acc[r + 0], acc[r + 1]);
      hv.y = pkf16(acc[r + 2], acc[r + 3]);
      *(uint2*)(VT16 + vb + r) = hv;
    }
  }
}

// ---------------------------------------------------------------------------
// MFMA flash attention, fixed softmax max (|q.k|<=1 after L2 norm => log2
// scores bounded by C1; 2^-C1 cancels in O/L). No max tracking, no rescale.
// grid (64 q-pairs, 8 bh), block 512 = 8 waves = 2 q-subtiles x 4 KV-splits.
// Wave (su,u): 32 queries (u), keys [su*1024, +1024) = 32 tiles of 32.
// QK^T: bf16 3-term (hi/lo); PV: fp16 single-term.
// Staging: double-buffered LDS via global_load_lds, flat 512-thread map,
// pre-swizzled global sources, linear LDS dest; reads apply same XOR.
// ---------------------------------------------------------------------------
__global__ __launch_bounds__(512, 4) void attn_kernel(
    const float* __restrict__ Qs,
    const u16* __restrict__ Khi, const u16* __restrict__ Klo,
    const u16* __restrict__ VT16, float* __restrict__ AO) {
  // [buf][split][plane: 0=Khi 1=Klo 2=V16][2048B]  = 48 KB total
  __shared__ __align__(16) char sbuf[2][4][3][2048];

  const int tid  = threadIdx.x;
  const int lane = tid & 63;
  const int w    = tid >> 6;
  const int su   = w & 3;           // KV split
  const int u    = w >> 2;          // q-subtile
  const int q    = lane & 31;
  const int hi   = lane >> 5;
  const int bh   = blockIdx.y;

  // ---- Q fragments (hi/lo truncation split); Q pre-scaled by C1 ----
  const int nrow = blockIdx.x * 64 + u * 32 + q;
  const float* qrow = Qs + ((size_t)bh * NB + nrow) * DH;
  short8 fqh[2], fql[2];
#pragma unroll
  for (int sl = 0; sl < 2; ++sl) {
    const int d0 = sl * 16 + hi * 8;
    const float4 a = *(const float4*)(qrow + d0);
    const float4 b = *(const float4*)(qrow + d0 + 4);
    fqh[sl] = mk8(pkhi(a.x, a.y), pkhi(a.z, a.w), pkhi(b.x, b.y), pkhi(b.z, b.w));
    fql[sl] = mk8(pkhi(a.x - tr16(a.x), a.y - tr16(a.y)),
                  pkhi(a.z - tr16(a.z), a.w - tr16(a.w)),
                  pkhi(b.x - tr16(b.x), b.y - tr16(b.y)),
                  pkhi(b.z - tr16(b.z), b.w - tr16(b.w)));
  }

  // ---- staging map: flat i = tid + it*512 over 12 planes x 2048B ----
  const u16* gp[3]; int gst[3], ldso[3];
#pragma unroll
  for (int it = 0; it < 3; ++it) {
    const int i    = tid + it * 512;
    const int pidx = i >> 7;            // plane 0..11 = split*3 + {Khi,Klo,V}
    const int sp   = pidx / 3;
    const int pl   = pidx - sp * 3;
    const int s    = i & 127;
    const int rtt  = s >> 2;            // row within plane (key or d)
    const int ps   = s & 3;             // physical 16B slot
    const int slot = ((ps ^ ((rtt >> 1) & 3)) << 3);   // logical, u16 units
    if (pl < 2) {   // K planes: row = key, advance 32 keys/tile
      const u16* base = pl ? Klo : Khi;
      gp[it]  = base + (size_t)bh * NB * DH + (size_t)(sp * 1024 + rtt) * DH + slot;
      gst[it] = 32 * DH;
    } else {        // V plane: row = d (NB-long), advance 32 u16/tile
      gp[it]  = VT16 + (size_t)bh * DH * NB + (size_t)rtt * NB + sp * 1024 + slot;
      gst[it] = 32;
    }
    ldso[it] = i * 16;
  }
  char* const sb = (char*)sbuf;
  auto stage = [&](int buf) {
#pragma unroll
    for (int it = 0; it < 3; ++it) {
      GL16(gp[it], sb + buf * 24576 + ldso[it]);
      gp[it] += gst[it];
    }
  };

  // read offsets (swizzled), constant per wave
  const int swq = (q >> 1) & 3;
  int koff[2];
#pragma unroll
  for (int i = 0; i < 2; ++i) koff[i] = q * 64 + (((i * 2 + hi) ^ swq) << 4);

  f32x16 oa;
#pragma unroll
  for (int r = 0; r < 16; ++r) oa[r] = 0.f;
  float lrun = 0.f;

  stage(0);
  __syncthreads();

  for (int t = 0; t < 32; ++t) {
    const int cur = t & 1;
    if (t < 31) stage(cur ^ 1);

    const char* cb  = sb + cur * 24576 + su * 6144;
    const char* ckh = cb;
    const char* ckl = cb + 2048;
    const char* cv  = cb + 4096;

    // ---- QK^T (3-term hi/lo bf16), S^T[key][q] ----
    f32x16 sa;
#pragma unroll
    for (int r = 0; r < 16; ++r) sa[r] = 0.f;
#pragma unroll
    for (int sl = 0; sl < 2; ++sl) {
      const short8 fkh = *(const short8*)(ckh + koff[sl]);
      const short8 fkl = *(const short8*)(ckl + koff[sl]);
      sa = __builtin_amdgcn_mfma_f32_32x32x16_bf16(fkh, fqh[sl], sa, 0, 0, 0);
      sa = __builtin_amdgcn_mfma_f32_32x32x16_bf16(fkl, fqh[sl], sa, 0, 0, 0);
      sa = __builtin_amdgcn_mfma_f32_32x32x16_bf16(fkh, fql[sl], sa, 0, 0, 0);
    }

    // ---- softmax, fixed max: raw v_exp_f32 (inputs bounded by ±2*C1) ----
    float e[16], lsum = 0.f;
#pragma unroll
    for (int r = 0; r < 16; ++r) {
      e[r] = __builtin_amdgcn_exp2f(sa[r]);
      lsum += e[r];
    }
    lrun += lsum;

    // ---- P pack (fp16 RTZ) + permlane32_swap distribution, PV 1-term ----
#pragma unroll
    for (int m = 0; m < 2; ++m) {
      const float* eb = e + 8 * m;
      unsigned x0 = pkf16(eb[0], eb[1]), x1 = pkf16(eb[2], eb[3]);
      unsigned y0 = pkf16(eb[4], eb[5]), y1 = pkf16(eb[6], eb[7]);
      pl32swap(x0, y0);    // distinct values: safe
      pl32swap(x1, y1);
      const f16x8 fP = mk8h(x0, x1, y0, y1);
      const f16x8 fv = *(const f16x8*)(cv + koff[m]);
      oa = __builtin_amdgcn_mfma_f32_32x32x16_f16(fv, fP, oa, 0, 0, 0);
    }
    __syncthreads();   // drains gload_lds (implicit vmcnt(0)) + LDS reads
  }

  // ---- 4-way split merge via LDS (plain sums — common fixed max) ----
  // Alias merge arrays onto the (dead) staging LDS.
  float* const mO = (float*)sbuf;             // [u][s(0..2)][q][33]
  float* const mL = mO + 2 * 3 * 32 * 33;     // [u][s][q]
  const float Lfull = lrun + __shfl_xor(lrun, 32);
  if (su != 0) {
    const int sidx = (u * 3 + (su - 1)) * 32 + q;
    if (hi == 0) mL[sidx] = Lfull;
#pragma unroll
    for (int r = 0; r < 16; ++r) {
      const int d = (r & 3) + 8 * (r >> 2) + 4 * hi;
      mO[sidx * 33 + d] = oa[r];
    }
  }
  __syncthreads();
  if (su == 0) {
    float Lt = Lfull;
#pragma unroll
    for (int s = 0; s < 3; ++s) Lt += mL[(u * 3 + s) * 32 + q];
    const float inv = 1.0f / Lt;
    const int b = bh >> 2, h = bh & 3;
    float* dst = AO + ((size_t)(b * NB + nrow)) * 128 + h * DH;
#pragma unroll
    for (int r = 0; r < 16; ++r) {
      const int d = (r & 3) + 8 * (r >> 2) + 4 * hi;
      float v = oa[r];
#pragma unroll
      for (int s = 0; s < 3; ++s) v += mO[((u * 3 + s) * 32 + q) * 33 + d];
      dst[d] = v * inv;
    }
  }
}

// ---------------------------------------------------------------------------
// out-proj GEMM: AO[8192][128] @ w_out[128][128] + b_out (in-place safe)
// ---------------------------------------------------------------------------
__global__ __launch_bounds__(128) void outproj_kernel(
    const float* __restrict__ AO, const float* __restrict__ w,
    const float* __restrict__ bias, float* __restrict__ out) {
  __shared__ float xT[128][36];
  const int tid = threadIdx.x;
  const int r0  = blockIdx.x * 32;

  for (int i = tid; i < 32 * 32; i += 128) {
    const int r = i >> 5, c4 = i & 31;
    const float4 v4 = ((const float4*)(AO + (size_t)(r0 + r) * 128))[c4];
    xT[c4 * 4 + 0][r] = v4.x;
    xT[c4 * 4 + 1][r] = v4.y;
    xT[c4 * 4 + 2][r] = v4.z;
    xT[c4 * 4 + 3][r] = v4.w;
  }
  __syncthreads();

  float acc[32];
#pragma unroll
  for (int r = 0; r < 32; ++r) acc[r] = 0.f;

  for (int c = 0; c < 128; ++c) {
    const float wv = w[c * 128 + tid];
#pragma unroll
    for (int r4 = 0; r4 < 8; ++r4) {
      const float4 xv = *(const float4*)&xT[c][r4 * 4];
      acc[r4 * 4 + 0] = fmaf(xv.x, wv, acc[r4 * 4 + 0]);
      acc[r4 * 4 + 1] = fmaf(xv.y, wv, acc[r4 * 4 + 1]);
      acc[r4 * 4 + 2] = fmaf(xv.z, wv, acc[r4 * 4 + 2]);
      acc[r4 * 4 + 3] = fmaf(xv.w, wv, acc[r4 * 4 + 3]);
    }
  }

  const float bv = bias[tid];
#pragma unroll
  for (int r = 0; r < 32; ++r) {
    out[(size_t)(r0 + r) * 128 + tid] = acc[r] + bv;
  }
}

// ---------------------------------------------------------------------------
extern "C" void kernel_launch(void* const* d_in, const int* in_sizes, int n_in,
                              void* d_out, int out_size, void* d_ws, size_t ws_size,
                              hipStream_t stream) {
  (void)in_sizes; (void)n_in; (void)out_size; (void)ws_size;
  const float* x     = (const float*)d_in[0];
  const float* w_qkv = (const float*)d_in[1];
  const float* w_out = (const float*)d_in[2];
  const float* b_out = (const float*)d_in[3];
  float* out = (float*)d_out;

  float* ws = (float*)d_ws;
  float* Qs = ws;                               // 4 MB fp32 [bh][n][32]
  u16* Khi  = (u16*)(ws + 1048576);             // 2 MB each
  u16* Klo  = Khi  + 1048576;
  u16* VT16 = Klo  + 1048576;
  float* AO = out;                              // in-place

  qkv_kernel<<<TOTROWS / 32, 384, 0, stream>>>(x, w_qkv, Qs, Khi, Klo, VT16);
  attn_kernel<<<dim3(NB / 64, BATCH * HEADS), 512, 0, stream>>>(Qs, Khi, Klo, VT16, AO);
  outproj_kernel<<<TOTROWS / 32, 128, 0, stream>>>(AO, w_out, b_out, out);
}

// Round 9
// 93.118 us; speedup vs baseline: 6.3150x; 1.1658x over previous
//
#include <hip/hip_runtime.h>
#include <math.h>

#define HEADS   4
#define DH      32
#define NB      4096      // tokens per batch (D*H*W)
#define BATCH   2
#define C_IN    128
#define QKV_COLS 384
#define TOTROWS 8192      // BATCH * NB
#define ATT_EPS 1e-12f
#define C1      14.42695040888963f   // SCALE * log2(e), prefolded into Q
#define QROWS   8         // rows per qkv block (grid 1024)
#define OROWS   8         // rows per outproj block (grid 1024)

typedef __attribute__((ext_vector_type(16))) float f32x16;
typedef __attribute__((ext_vector_type(8)))  short short8;
typedef _Float16 f16x8 __attribute__((ext_vector_type(8)));
typedef __fp16 fp16x2 __attribute__((ext_vector_type(2)));   // cvt_pkrtz return type
typedef unsigned short u16;

__device__ __forceinline__ float tr16(float a) {        // truncate to bf16 (bits)
  return __uint_as_float(__float_as_uint(a) & 0xFFFF0000u);
}
__device__ __forceinline__ unsigned pkhi(float a, float b) {  // pack 2 bf16 (trunc)
  return (__float_as_uint(a) >> 16) | (__float_as_uint(b) & 0xFFFF0000u);
}
__device__ __forceinline__ u16 b16(float a) {
  return (u16)(__float_as_uint(a) >> 16);
}
// pack 2 f32 -> 2 f16 (RTZ), single instruction
union Uh2 { fp16x2 h; unsigned u; };
__device__ __forceinline__ unsigned pkf16(float a, float b) {
  Uh2 t; t.h = __builtin_amdgcn_cvt_pkrtz(a, b); return t.u;
}
union U8 { unsigned u[4]; short8 s8; };
__device__ __forceinline__ short8 mk8(unsigned a, unsigned b, unsigned c, unsigned d) {
  U8 t; t.u[0] = a; t.u[1] = b; t.u[2] = c; t.u[3] = d; return t.s8;
}
union U8h { unsigned u[4]; f16x8 h8; };
__device__ __forceinline__ f16x8 mk8h(unsigned a, unsigned b, unsigned c, unsigned d) {
  U8h t; t.u[0] = a; t.u[1] = b; t.u[2] = c; t.u[3] = d; return t.h8;
}
// v_permlane32_swap_b32 a,b. SAFE ONLY when a and b hold distinct values
// (else regalloc may coalesce them into one register) — see R4 post-mortem.
__device__ __forceinline__ void pl32swap(unsigned& a, unsigned& b) {
  asm("v_permlane32_swap_b32 %0, %1" : "+v"(a), "+v"(b));
}
#define GL16(gp, lp)                                                        \
  __builtin_amdgcn_global_load_lds(                                         \
      (const __attribute__((address_space(1))) void*)(gp),                  \
      (__attribute__((address_space(3))) void*)(lp), 16, 0, 0)

// ---------------------------------------------------------------------------
// QKV GEMM (x @ w_qkv) + fused L2-normalize of q,k. 8 rows/block, 1024 blocks
// (24 waves/CU — R8 showed 32-row/256-block version was grid-starved at 13%
// occupancy, 12% VALUBusy). float4 partial accumulators break the serial
// FMA dependence chain. Writes:
//   Qs  fp32 [bh][n][32], pre-scaled by C1
//   Khi/Klo u16 [bh][n][32]   (bf16 truncation hi + residual lo)
//   VT16 u16 [bh][32][n]      (fp16 RTZ, pre-transposed)
// ---------------------------------------------------------------------------
__global__ __launch_bounds__(384) void qkv_kernel(
    const float* __restrict__ x, const float* __restrict__ w,
    float* __restrict__ Qs, u16* __restrict__ Khi, u16* __restrict__ Klo,
    u16* __restrict__ VT16) {
  __shared__ float xR[QROWS][132];   // row-major tile, 528B rows (16B-aligned)
  const int tid = threadIdx.x;
  const int r0  = blockIdx.x * QROWS;

  if (tid < QROWS * 32) {
    const int r = tid >> 5, c4 = tid & 31;
    const float4 v4 = ((const float4*)(x + (size_t)(r0 + r) * C_IN))[c4];
    *(float4*)&xR[r][c4 * 4] = v4;
  }
  __syncthreads();

  float4 a4[QROWS];
#pragma unroll
  for (int r = 0; r < QROWS; ++r) a4[r] = make_float4(0.f, 0.f, 0.f, 0.f);

  for (int c4 = 0; c4 < 32; ++c4) {
    const float wv0 = w[(c4 * 4 + 0) * QKV_COLS + tid];
    const float wv1 = w[(c4 * 4 + 1) * QKV_COLS + tid];
    const float wv2 = w[(c4 * 4 + 2) * QKV_COLS + tid];
    const float wv3 = w[(c4 * 4 + 3) * QKV_COLS + tid];
#pragma unroll
    for (int r = 0; r < QROWS; ++r) {
      const float4 xv = *(const float4*)&xR[r][c4 * 4];   // broadcast read
      a4[r].x = fmaf(xv.x, wv0, a4[r].x);
      a4[r].y = fmaf(xv.y, wv1, a4[r].y);
      a4[r].z = fmaf(xv.z, wv2, a4[r].z);
      a4[r].w = fmaf(xv.w, wv3, a4[r].w);
    }
  }

  float acc[QROWS];
#pragma unroll
  for (int r = 0; r < QROWS; ++r)
    acc[r] = (a4[r].x + a4[r].y) + (a4[r].z + a4[r].w);

  const int part = tid >> 7;   // 0=q 1=k 2=v (wave-uniform)
  if (part < 2) {
#pragma unroll
    for (int r = 0; r < QROWS; ++r) {
      float s = acc[r] * acc[r];
      s += __shfl_xor(s, 1, 32);
      s += __shfl_xor(s, 2, 32);
      s += __shfl_xor(s, 4, 32);
      s += __shfl_xor(s, 8, 32);
      s += __shfl_xor(s, 16, 32);
      acc[r] *= 1.0f / fmaxf(sqrtf(s), ATT_EPS);
    }
  }

  const int h = (tid >> 5) & 3, d = tid & 31;
  const int b = r0 >> 12, n0 = r0 & (NB - 1);
  const int bh = b * HEADS + h;
  if (part == 0) {
    float* dst = Qs + ((size_t)bh * NB + n0) * DH + d;
#pragma unroll
    for (int r = 0; r < QROWS; ++r) dst[(size_t)r * DH] = acc[r] * C1;
  } else if (part == 1) {
    const size_t kb = ((size_t)bh * NB + n0) * DH + d;
#pragma unroll
    for (int r = 0; r < QROWS; ++r) {
      const float kv = acc[r];
      Khi[kb + (size_t)r * DH] = b16(kv);
      Klo[kb + (size_t)r * DH] = b16(kv - tr16(kv));
    }
  } else {
    const size_t vb = ((size_t)bh * DH + d) * NB + n0;
#pragma unroll
    for (int r = 0; r < QROWS; r += 4) {
      uint2 hv;
      hv.x = pkf16(acc[r + 0], acc[r + 1]);
      hv.y = pkf16(acc[r + 2], acc[r + 3]);
      *(uint2*)(VT16 + vb + r) = hv;
    }
  }
}

// ---------------------------------------------------------------------------
// MFMA flash attention, fixed softmax max (|q.k|<=1 after L2 norm => log2
// scores bounded by C1; 2^-C1 cancels in O/L). No max tracking, no rescale.
// grid (64 q-pairs, 8 bh), block 512 = 8 waves = 2 q-subtiles x 4 KV-splits.
// QK^T: bf16 3-term (hi/lo); PV: fp16 single-term. (unchanged from R8)
// ---------------------------------------------------------------------------
__global__ __launch_bounds__(512, 4) void attn_kernel(
    const float* __restrict__ Qs,
    const u16* __restrict__ Khi, const u16* __restrict__ Klo,
    const u16* __restrict__ VT16, float* __restrict__ AO) {
  // [buf][split][plane: 0=Khi 1=Klo 2=V16][2048B]  = 48 KB total
  __shared__ __align__(16) char sbuf[2][4][3][2048];

  const int tid  = threadIdx.x;
  const int lane = tid & 63;
  const int w    = tid >> 6;
  const int su   = w & 3;           // KV split
  const int u    = w >> 2;          // q-subtile
  const int q    = lane & 31;
  const int hi   = lane >> 5;
  const int bh   = blockIdx.y;

  // ---- Q fragments (hi/lo truncation split); Q pre-scaled by C1 ----
  const int nrow = blockIdx.x * 64 + u * 32 + q;
  const float* qrow = Qs + ((size_t)bh * NB + nrow) * DH;
  short8 fqh[2], fql[2];
#pragma unroll
  for (int sl = 0; sl < 2; ++sl) {
    const int d0 = sl * 16 + hi * 8;
    const float4 a = *(const float4*)(qrow + d0);
    const float4 b = *(const float4*)(qrow + d0 + 4);
    fqh[sl] = mk8(pkhi(a.x, a.y), pkhi(a.z, a.w), pkhi(b.x, b.y), pkhi(b.z, b.w));
    fql[sl] = mk8(pkhi(a.x - tr16(a.x), a.y - tr16(a.y)),
                  pkhi(a.z - tr16(a.z), a.w - tr16(a.w)),
                  pkhi(b.x - tr16(b.x), b.y - tr16(b.y)),
                  pkhi(b.z - tr16(b.z), b.w - tr16(b.w)));
  }

  // ---- staging map: flat i = tid + it*512 over 12 planes x 2048B ----
  const u16* gp[3]; int gst[3], ldso[3];
#pragma unroll
  for (int it = 0; it < 3; ++it) {
    const int i    = tid + it * 512;
    const int pidx = i >> 7;            // plane 0..11 = split*3 + {Khi,Klo,V}
    const int sp   = pidx / 3;
    const int pl   = pidx - sp * 3;
    const int s    = i & 127;
    const int rtt  = s >> 2;            // row within plane (key or d)
    const int ps   = s & 3;             // physical 16B slot
    const int slot = ((ps ^ ((rtt >> 1) & 3)) << 3);   // logical, u16 units
    if (pl < 2) {   // K planes: row = key, advance 32 keys/tile
      const u16* base = pl ? Klo : Khi;
      gp[it]  = base + (size_t)bh * NB * DH + (size_t)(sp * 1024 + rtt) * DH + slot;
      gst[it] = 32 * DH;
    } else {        // V plane: row = d (NB-long), advance 32 u16/tile
      gp[it]  = VT16 + (size_t)bh * DH * NB + (size_t)rtt * NB + sp * 1024 + slot;
      gst[it] = 32;
    }
    ldso[it] = i * 16;
  }
  char* const sb = (char*)sbuf;
  auto stage = [&](int buf) {
#pragma unroll
    for (int it = 0; it < 3; ++it) {
      GL16(gp[it], sb + buf * 24576 + ldso[it]);
      gp[it] += gst[it];
    }
  };

  // read offsets (swizzled), constant per wave
  const int swq = (q >> 1) & 3;
  int koff[2];
#pragma unroll
  for (int i = 0; i < 2; ++i) koff[i] = q * 64 + (((i * 2 + hi) ^ swq) << 4);

  f32x16 oa;
#pragma unroll
  for (int r = 0; r < 16; ++r) oa[r] = 0.f;
  float lrun = 0.f;

  stage(0);
  __syncthreads();

  for (int t = 0; t < 32; ++t) {
    const int cur = t & 1;
    if (t < 31) stage(cur ^ 1);

    const char* cb  = sb + cur * 24576 + su * 6144;
    const char* ckh = cb;
    const char* ckl = cb + 2048;
    const char* cv  = cb + 4096;

    // ---- QK^T (3-term hi/lo bf16), S^T[key][q] ----
    f32x16 sa;
#pragma unroll
    for (int r = 0; r < 16; ++r) sa[r] = 0.f;
#pragma unroll
    for (int sl = 0; sl < 2; ++sl) {
      const short8 fkh = *(const short8*)(ckh + koff[sl]);
      const short8 fkl = *(const short8*)(ckl + koff[sl]);
      sa = __builtin_amdgcn_mfma_f32_32x32x16_bf16(fkh, fqh[sl], sa, 0, 0, 0);
      sa = __builtin_amdgcn_mfma_f32_32x32x16_bf16(fkl, fqh[sl], sa, 0, 0, 0);
      sa = __builtin_amdgcn_mfma_f32_32x32x16_bf16(fkh, fql[sl], sa, 0, 0, 0);
    }

    // ---- softmax, fixed max: raw v_exp_f32 (inputs bounded by ±2*C1) ----
    float e[16], lsum = 0.f;
#pragma unroll
    for (int r = 0; r < 16; ++r) {
      e[r] = __builtin_amdgcn_exp2f(sa[r]);
      lsum += e[r];
    }
    lrun += lsum;

    // ---- P pack (fp16 RTZ) + permlane32_swap distribution, PV 1-term ----
#pragma unroll
    for (int m = 0; m < 2; ++m) {
      const float* eb = e + 8 * m;
      unsigned x0 = pkf16(eb[0], eb[1]), x1 = pkf16(eb[2], eb[3]);
      unsigned y0 = pkf16(eb[4], eb[5]), y1 = pkf16(eb[6], eb[7]);
      pl32swap(x0, y0);    // distinct values: safe
      pl32swap(x1, y1);
      const f16x8 fP = mk8h(x0, x1, y0, y1);
      const f16x8 fv = *(const f16x8*)(cv + koff[m]);
      oa = __builtin_amdgcn_mfma_f32_32x32x16_f16(fv, fP, oa, 0, 0, 0);
    }
    __syncthreads();   // drains gload_lds (implicit vmcnt(0)) + LDS reads
  }

  // ---- 4-way split merge via LDS (plain sums — common fixed max) ----
  // Alias merge arrays onto the (dead) staging LDS.
  float* const mO = (float*)sbuf;             // [u][s(0..2)][q][33]
  float* const mL = mO + 2 * 3 * 32 * 33;     // [u][s][q]
  const float Lfull = lrun + __shfl_xor(lrun, 32);
  if (su != 0) {
    const int sidx = (u * 3 + (su - 1)) * 32 + q;
    if (hi == 0) mL[sidx] = Lfull;
#pragma unroll
    for (int r = 0; r < 16; ++r) {
      const int d = (r & 3) + 8 * (r >> 2) + 4 * hi;
      mO[sidx * 33 + d] = oa[r];
    }
  }
  __syncthreads();
  if (su == 0) {
    float Lt = Lfull;
#pragma unroll
    for (int s = 0; s < 3; ++s) Lt += mL[(u * 3 + s) * 32 + q];
    const float inv = 1.0f / Lt;
    const int b = bh >> 2, h = bh & 3;
    float* dst = AO + ((size_t)(b * NB + nrow)) * 128 + h * DH;
#pragma unroll
    for (int r = 0; r < 16; ++r) {
      const int d = (r & 3) + 8 * (r >> 2) + 4 * hi;
      float v = oa[r];
#pragma unroll
      for (int s = 0; s < 3; ++s) v += mO[((u * 3 + s) * 32 + q) * 33 + d];
      dst[d] = v * inv;
    }
  }
}

// ---------------------------------------------------------------------------
// out-proj GEMM: AO[8192][128] @ w_out[128][128] + b_out (in-place safe:
// block stages its 8 rows in LDS before overwriting them). 1024 blocks
// (R8's 256-block/2-wave version was 2 waves/CU).
// ---------------------------------------------------------------------------
__global__ __launch_bounds__(128) void outproj_kernel(
    const float* __restrict__ AO, const float* __restrict__ w,
    const float* __restrict__ bias, float* __restrict__ out) {
  __shared__ float xR[OROWS][132];
  const int tid = threadIdx.x;
  const int r0  = blockIdx.x * OROWS;

  for (int i = tid; i < OROWS * 32; i += 128) {
    const int r = i >> 5, c4 = i & 31;
    const float4 v4 = ((const float4*)(AO + (size_t)(r0 + r) * 128))[c4];
    *(float4*)&xR[r][c4 * 4] = v4;
  }
  __syncthreads();

  float4 a4[OROWS];
#pragma unroll
  for (int r = 0; r < OROWS; ++r) a4[r] = make_float4(0.f, 0.f, 0.f, 0.f);

  for (int c4 = 0; c4 < 32; ++c4) {
    const float wv0 = w[(c4 * 4 + 0) * 128 + tid];
    const float wv1 = w[(c4 * 4 + 1) * 128 + tid];
    const float wv2 = w[(c4 * 4 + 2) * 128 + tid];
    const float wv3 = w[(c4 * 4 + 3) * 128 + tid];
#pragma unroll
    for (int r = 0; r < OROWS; ++r) {
      const float4 xv = *(const float4*)&xR[r][c4 * 4];   // broadcast read
      a4[r].x = fmaf(xv.x, wv0, a4[r].x);
      a4[r].y = fmaf(xv.y, wv1, a4[r].y);
      a4[r].z = fmaf(xv.z, wv2, a4[r].z);
      a4[r].w = fmaf(xv.w, wv3, a4[r].w);
    }
  }

  const float bv = bias[tid];
#pragma unroll
  for (int r = 0; r < OROWS; ++r) {
    const float acc = (a4[r].x + a4[r].y) + (a4[r].z + a4[r].w);
    out[(size_t)(r0 + r) * 128 + tid] = acc + bv;
  }
}

// ---------------------------------------------------------------------------
extern "C" void kernel_launch(void* const* d_in, const int* in_sizes, int n_in,
                              void* d_out, int out_size, void* d_ws, size_t ws_size,
                              hipStream_t stream) {
  (void)in_sizes; (void)n_in; (void)out_size; (void)ws_size;
  const float* x     = (const float*)d_in[0];
  const float* w_qkv = (const float*)d_in[1];
  const float* w_out = (const float*)d_in[2];
  const float* b_out = (const float*)d_in[3];
  float* out = (float*)d_out;

  float* ws = (float*)d_ws;
  float* Qs = ws;                               // 4 MB fp32 [bh][n][32]
  u16* Khi  = (u16*)(ws + 1048576);             // 2 MB each
  u16* Klo  = Khi  + 1048576;
  u16* VT16 = Klo  + 1048576;
  float* AO = out;                              // in-place

  qkv_kernel<<<TOTROWS / QROWS, 384, 0, stream>>>(x, w_qkv, Qs, Khi, Klo, VT16);
  attn_kernel<<<dim3(NB / 64, BATCH * HEADS), 512, 0, stream>>>(Qs, Khi, Klo, VT16, AO);
  outproj_kernel<<<TOTROWS / OROWS, 128, 0, stream>>>(AO, w_out, b_out, out);
}